// Round 2
// baseline (3130.484 us; speedup 1.0000x reference)
//
#include <hip/hip_runtime.h>
#include <hip/hip_bf16.h>

// Problem constants
#define BB   2048
#define NUU  20000
#define NFF  100000
#define NAA  20000
#define DD   150
#define DKK  64

static constexpr int EXPERT_W  = 1774;        // 5*150 + 10*64 + 256 + 128
static constexpr int X_OFF     = 1390;        // user_x_user offset in expert row
static constexpr int W_OFF     = 1646;        // user_w_user offset in expert row
static constexpr int EXPERT_SZ = BB * EXPERT_W;   // 3,633,152
static constexpr int OH_BASE   = EXPERT_SZ;       // one_hot region
static constexpr int FM_BASE   = OH_BASE + BB * 3;// fm region (flat (4,B,D) order)

// ---------------------------------------------------------------------------
// Kernel 1: all gathers -> expert row segments, one_hot, fm copies.
// One block per batch element. OUTPUT IS FLOAT32.
// ---------------------------------------------------------------------------
__global__ __launch_bounds__(256) void gather_kernel(
    const int* __restrict__ inputs, const int* __restrict__ shifts,
    const float* __restrict__ Wuf, const float* __restrict__ Wfu,
    const float* __restrict__ Wua, const float* __restrict__ Wau,
    const float* __restrict__ Wfe,
    const float* __restrict__ Wut, const float* __restrict__ Wuk1, const float* __restrict__ Wuk2,
    const float* __restrict__ Wft, const float* __restrict__ Wfk1, const float* __restrict__ Wfk2,
    const float* __restrict__ Wufd, const float* __restrict__ Wfud,
    const float* __restrict__ Wuad, const float* __restrict__ Waud,
    float* __restrict__ out)
{
    const int b = blockIdx.x;
    const int u = inputs[b*3 + 0];
    const int f = inputs[b*3 + 1];
    const int a = inputs[b*3 + 2];
    float* row = out + b * EXPERT_W;
    float* fm  = out + FM_BASE;
    const int t = threadIdx.x;

    for (int c = t; c < DD; c += 256) {
        float ufe = Wuf[u*DD + c];
        float uae = Wua[u*DD + c];
        float fue = Wfu[f*DD + c];
        float fee = Wfe[f*DD + c];
        float aue = Wau[a*DD + c];
        row[0    + c] = ufe;
        row[150  + c] = uae;
        row[620  + c] = fue;
        row[898  + c] = fee;
        row[1176 + c] = aue;
        // fm = stack([ufe, uae, fue, aue], axis=0) flattened (4, B, D)
        fm[0*BB*DD + b*DD + c] = ufe;
        fm[1*BB*DD + b*DD + c] = uae;
        fm[2*BB*DD + b*DD + c] = fue;
        fm[3*BB*DD + b*DD + c] = aue;
    }
    for (int c = t; c < DKK; c += 256) {
        row[300  + c] = Wut [u*DKK + c];
        row[364  + c] = Wuk1[u*DKK + c];
        row[428  + c] = Wuk2[u*DKK + c];
        row[492  + c] = Wufd[u*DKK + c];   // user_feed_d2vem
        row[556  + c] = Wuad[u*DKK + c];   // user_author_d2vem
        row[770  + c] = Wft [f*DKK + c];
        row[834  + c] = Wfk1[f*DKK + c];
        row[1048 + c] = Wfk2[f*DKK + c];
        row[1112 + c] = Wfud[f*DKK + c];   // feed_user_d2vem
        row[1326 + c] = Waud[a*DKK + c];   // author_user_d2vem
    }
    if (t < 3) {
        out[OH_BASE + b*3 + t] = (float)(inputs[b*3 + t] + shifts[t]);
    }
}

// ---------------------------------------------------------------------------
// Kernel 2: user_x_user = relu(vec(outer products) @ W256 + b256)
// Block: 16 batches x 128 k-columns. 256 threads = 16 b-lanes x 16 kg.
// Each thread accumulates 8 k-outputs for one batch.
// ---------------------------------------------------------------------------
static constexpr int NPAIR_X = 300 * 150;   // 45000
static constexpr int CHX     = 128;         // pair chunk

__global__ __launch_bounds__(256) void xuser_kernel(
    const int* __restrict__ inputs,
    const float* __restrict__ Wuf, const float* __restrict__ Wua,
    const float* __restrict__ Wfu, const float* __restrict__ Wau,
    const float* __restrict__ W256, const float* __restrict__ b256,
    float* __restrict__ out)
{
    __shared__ float xs[16][308];   // [0,150)=ufe, [150,300)=uae
    __shared__ float ys[16][308];   // [0,150)=fue, [150,300)=aue
    __shared__ float xy[CHX][16];

    const int half = blockIdx.x & 1;       // which 128-wide k half
    const int bg   = blockIdx.x >> 1;      // batch group 0..127
    const int b0   = bg * 16;
    const int t    = threadIdx.x;
    const int bl   = t & 15;
    const int kg   = t >> 4;
    const int kbase = half * 128 + kg * 8;

    for (int idx = t; idx < 16 * DD; idx += 256) {
        int bb = idx / DD;
        int c  = idx - bb * DD;
        int u = inputs[(b0+bb)*3 + 0];
        int f = inputs[(b0+bb)*3 + 1];
        int a = inputs[(b0+bb)*3 + 2];
        xs[bb][c]       = Wuf[u*DD + c];
        xs[bb][150 + c] = Wua[u*DD + c];
        ys[bb][c]       = Wfu[f*DD + c];
        ys[bb][150 + c] = Wau[a*DD + c];
    }

    float acc[8] = {0.f,0.f,0.f,0.f,0.f,0.f,0.f,0.f};

    for (int base = 0; base < NPAIR_X; base += CHX) {
        __syncthreads();   // staging done / previous chunk's readers done
        #pragma unroll
        for (int r = 0; r < (CHX*16)/256; ++r) {     // 8 xy values per thread
            int idx = t + r * 256;
            int pl  = idx >> 4;
            int bb  = idx & 15;
            int p   = base + pl;
            if (p < NPAIR_X) {
                int i = p / 150;
                int j = p - i * 150;
                xy[pl][bb] = xs[bb][i] * ys[bb][(i >= 150 ? 150 : 0) + j];
            }
        }
        __syncthreads();
        const int lim = min(CHX, NPAIR_X - base);
        const float* wp = W256 + base * 256 + kbase;
        for (int pl = 0; pl < lim; ++pl) {
            float s = xy[pl][bl];                       // LDS broadcast across kg
            const float4* w4 = (const float4*)(wp + pl * 256);
            float4 w0 = w4[0];
            float4 w1 = w4[1];
            acc[0] = fmaf(s, w0.x, acc[0]);
            acc[1] = fmaf(s, w0.y, acc[1]);
            acc[2] = fmaf(s, w0.z, acc[2]);
            acc[3] = fmaf(s, w0.w, acc[3]);
            acc[4] = fmaf(s, w1.x, acc[4]);
            acc[5] = fmaf(s, w1.y, acc[5]);
            acc[6] = fmaf(s, w1.z, acc[6]);
            acc[7] = fmaf(s, w1.w, acc[7]);
        }
    }

    const int rowbase = (b0 + bl) * EXPERT_W + X_OFF;
    #pragma unroll
    for (int m = 0; m < 8; ++m) {
        float v = acc[m] + b256[kbase + m];
        out[rowbase + kbase + m] = (v > 0.f ? v : 0.f);
    }
}

// ---------------------------------------------------------------------------
// Kernel 3: user_w_user = relu(vec(outer products) @ W128 + b128)
// Block: 8 batches x all 128 k. 256 threads = 8 b-lanes x 32 kg, 4 k each.
// ---------------------------------------------------------------------------
static constexpr int NPAIR_W = 128 * 64;    // 8192
static constexpr int CHW     = 256;

__global__ __launch_bounds__(256) void wuser_kernel(
    const int* __restrict__ inputs,
    const float* __restrict__ Wufd, const float* __restrict__ Wuad,
    const float* __restrict__ Wfud, const float* __restrict__ Waud,
    const float* __restrict__ W128, const float* __restrict__ b128,
    float* __restrict__ out)
{
    __shared__ float xs[8][132];    // [0,64)=uf_d2v, [64,128)=ua_d2v
    __shared__ float ys[8][132];    // [0,64)=fu_d2v, [64,128)=au_d2v
    __shared__ float xy[CHW][8];

    const int bg = blockIdx.x;
    const int b0 = bg * 8;
    const int t  = threadIdx.x;
    const int bl = t & 7;
    const int kg = t >> 3;          // 0..31
    const int kbase = kg * 4;

    for (int idx = t; idx < 8 * DKK; idx += 256) {
        int bb = idx >> 6;
        int c  = idx & 63;
        int u = inputs[(b0+bb)*3 + 0];
        int f = inputs[(b0+bb)*3 + 1];
        int a = inputs[(b0+bb)*3 + 2];
        xs[bb][c]      = Wufd[u*DKK + c];
        xs[bb][64 + c] = Wuad[u*DKK + c];
        ys[bb][c]      = Wfud[f*DKK + c];
        ys[bb][64 + c] = Waud[a*DKK + c];
    }

    float acc[4] = {0.f,0.f,0.f,0.f};

    for (int base = 0; base < NPAIR_W; base += CHW) {
        __syncthreads();
        #pragma unroll
        for (int r = 0; r < (CHW*8)/256; ++r) {      // 8 xy values per thread
            int idx = t + r * 256;
            int pl  = idx >> 3;
            int bb  = idx & 7;
            int p   = base + pl;
            int i = p >> 6;
            int j = p & 63;
            xy[pl][bb] = xs[bb][i] * ys[bb][(i >= 64 ? 64 : 0) + j];
        }
        __syncthreads();
        const float* wp = W128 + base * 128 + kbase;
        for (int pl = 0; pl < CHW; ++pl) {
            float s = xy[pl][bl];
            float4 w = *(const float4*)(wp + pl * 128);
            acc[0] = fmaf(s, w.x, acc[0]);
            acc[1] = fmaf(s, w.y, acc[1]);
            acc[2] = fmaf(s, w.z, acc[2]);
            acc[3] = fmaf(s, w.w, acc[3]);
        }
    }

    const int rowbase = (b0 + bl) * EXPERT_W + W_OFF;
    #pragma unroll
    for (int m = 0; m < 4; ++m) {
        float v = acc[m] + b128[kbase + m];
        out[rowbase + kbase + m] = (v > 0.f ? v : 0.f);
    }
}

// ---------------------------------------------------------------------------
extern "C" void kernel_launch(void* const* d_in, const int* in_sizes, int n_in,
                              void* d_out, int out_size, void* d_ws, size_t ws_size,
                              hipStream_t stream)
{
    const int*   inputs = (const int*)  d_in[0];
    const int*   shifts = (const int*)  d_in[1];
    const float* Wuf    = (const float*)d_in[2];   // W_user_feed   (NU,150)
    const float* Wfu    = (const float*)d_in[3];   // W_feed_user   (NF,150)
    const float* Wua    = (const float*)d_in[4];   // W_user_author (NU,150)
    const float* Wau    = (const float*)d_in[5];   // W_author_user (NA,150)
    const float* Wfe    = (const float*)d_in[6];   // W_feed_emb    (NF,150)
    const float* Wut    = (const float*)d_in[7];   // W_user_tag    (NU,64)
    const float* Wuk1   = (const float*)d_in[8];
    const float* Wuk2   = (const float*)d_in[9];
    const float* Wft    = (const float*)d_in[10];
    const float* Wfk1   = (const float*)d_in[11];
    const float* Wfk2   = (const float*)d_in[12];
    const float* Wufd   = (const float*)d_in[13];  // W_uf_d2v (NU,64)
    const float* Wfud   = (const float*)d_in[14];  // W_fu_d2v (NF,64)
    const float* Wuad   = (const float*)d_in[15];  // W_ua_d2v (NU,64)
    const float* Waud   = (const float*)d_in[16];  // W_au_d2v (NA,64)
    const float* W256   = (const float*)d_in[17];  // (45000,256)
    const float* b256   = (const float*)d_in[18];
    const float* W128   = (const float*)d_in[19];  // (8192,128)
    const float* b128   = (const float*)d_in[20];

    float* out = (float*)d_out;

    gather_kernel<<<BB, 256, 0, stream>>>(inputs, shifts,
        Wuf, Wfu, Wua, Wau, Wfe, Wut, Wuk1, Wuk2, Wft, Wfk1, Wfk2,
        Wufd, Wfud, Wuad, Waud, out);

    // 128 batch-groups x 2 k-halves = 256 blocks
    xuser_kernel<<<256, 256, 0, stream>>>(inputs, Wuf, Wua, Wfu, Wau, W256, b256, out);

    // 256 batch-groups
    wuser_kernel<<<256, 256, 0, stream>>>(inputs, Wufd, Wuad, Wfud, Waud, W128, b128, out);
}

// Round 3
// 286.439 us; speedup vs baseline: 10.9290x; 10.9290x over previous
//
#include <hip/hip_runtime.h>
#include <hip/hip_bf16.h>

#define BB   2048
#define DD   150
#define DKK  64

static constexpr int EXPERT_W  = 1774;        // 5*150 + 10*64 + 256 + 128
static constexpr int X_OFF     = 1390;
static constexpr int W_OFF     = 1646;
static constexpr int EXPERT_SZ = BB * EXPERT_W;
static constexpr int OH_BASE   = EXPERT_SZ;
static constexpr int FM_BASE   = OH_BASE + BB * 3;

// ---- workspace layout (bytes) ----
static constexpr size_t WTX_OFF = 0;               // bf16 [256][48000]  (p' = i*160+j, zero pad j>=150)
static constexpr size_t WTW_OFF = 24576000;        // bf16 [128][8192]
static constexpr size_t WSX_OFF = 26673152;        // f32  [16][2048][256] partials
static constexpr size_t WSW_OFF = 60227584;        // f32  [16][2048][128] partials
static constexpr size_t WS_NEED = 77004800;

typedef __attribute__((ext_vector_type(8))) short bf16x8;
typedef __attribute__((ext_vector_type(4))) float f32x4;
typedef __attribute__((ext_vector_type(4))) int   i32x4;

union APack { int d[4]; bf16x8 v; };

__device__ __forceinline__ int cvtpk_bf16(float a, float b) {
  int r; asm("v_cvt_pk_bf16_f32 %0, %1, %2" : "=v"(r) : "v"(a), "v"(b)); return r;
}
__device__ __forceinline__ f32x4 mfma16(bf16x8 a, bf16x8 b, f32x4 c) {
  return __builtin_amdgcn_mfma_f32_16x16x32_bf16(a, b, c, 0, 0, 0);
}
// yv: 4 dwords = 8 bf16 ascending k; build A elems a.d[e] = pack(x*y[2e], x*y[2e+1])
__device__ __forceinline__ void build_a(const i32x4 yv, float xv, APack& a) {
  #pragma unroll
  for (int e = 0; e < 4; ++e) {
    float ylo = __int_as_float(yv[e] << 16);
    float yhi = __int_as_float(yv[e] & 0xffff0000);
    a.d[e] = cvtpk_bf16(xv * ylo, xv * yhi);
  }
}

// ---------------------------------------------------------------------------
// Kernel 1: gathers -> expert row segments, one_hot, fm copies (f32 out).
// ---------------------------------------------------------------------------
__global__ __launch_bounds__(256) void gather_kernel(
    const int* __restrict__ inputs, const int* __restrict__ shifts,
    const float* __restrict__ Wuf, const float* __restrict__ Wfu,
    const float* __restrict__ Wua, const float* __restrict__ Wau,
    const float* __restrict__ Wfe,
    const float* __restrict__ Wut, const float* __restrict__ Wuk1, const float* __restrict__ Wuk2,
    const float* __restrict__ Wft, const float* __restrict__ Wfk1, const float* __restrict__ Wfk2,
    const float* __restrict__ Wufd, const float* __restrict__ Wfud,
    const float* __restrict__ Wuad, const float* __restrict__ Waud,
    float* __restrict__ out)
{
    const int b = blockIdx.x;
    const int u = inputs[b*3 + 0];
    const int f = inputs[b*3 + 1];
    const int a = inputs[b*3 + 2];
    float* row = out + b * EXPERT_W;
    float* fm  = out + FM_BASE;
    const int t = threadIdx.x;

    for (int c = t; c < DD; c += 256) {
        float ufe = Wuf[u*DD + c];
        float uae = Wua[u*DD + c];
        float fue = Wfu[f*DD + c];
        float fee = Wfe[f*DD + c];
        float aue = Wau[a*DD + c];
        row[0    + c] = ufe;
        row[150  + c] = uae;
        row[620  + c] = fue;
        row[898  + c] = fee;
        row[1176 + c] = aue;
        fm[0*BB*DD + b*DD + c] = ufe;
        fm[1*BB*DD + b*DD + c] = uae;
        fm[2*BB*DD + b*DD + c] = fue;
        fm[3*BB*DD + b*DD + c] = aue;
    }
    for (int c = t; c < DKK; c += 256) {
        row[300  + c] = Wut [u*DKK + c];
        row[364  + c] = Wuk1[u*DKK + c];
        row[428  + c] = Wuk2[u*DKK + c];
        row[492  + c] = Wufd[u*DKK + c];
        row[556  + c] = Wuad[u*DKK + c];
        row[770  + c] = Wft [f*DKK + c];
        row[834  + c] = Wfk1[f*DKK + c];
        row[1048 + c] = Wfk2[f*DKK + c];
        row[1112 + c] = Wfud[f*DKK + c];
        row[1326 + c] = Waud[a*DKK + c];
    }
    if (t < 3) {
        out[OH_BASE + b*3 + t] = (float)(inputs[b*3 + t] + shifts[t]);
    }
}

// ---------------------------------------------------------------------------
// Transpose + bf16 cast:  W[p][n] f32  ->  Wt[n][p'] bf16, p' = i*JDIV + j,
// source p = i*JLIM + j, zero for j >= JLIM. 64x64 tiles.
// ---------------------------------------------------------------------------
template<int NC, int PLOUT, int JDIV, int JLIM>
__global__ __launch_bounds__(256) void transpose_kernel(
    const float* __restrict__ W, __hip_bfloat16* __restrict__ Wt)
{
  __shared__ float tile[64][69];
  const int ntn = NC / 64;
  const int bp = blockIdx.x / ntn;
  const int bn = blockIdx.x - bp * ntn;
  const int p0 = bp * 64, n0 = bn * 64;
  const int t = threadIdx.x;
  const int c = t & 63, r4 = t >> 6;
  #pragma unroll 4
  for (int rr = 0; rr < 16; ++rr) {
    int pr = rr*4 + r4;
    int pp = p0 + pr;
    int i = pp / JDIV, j = pp - i * JDIV;
    float v = 0.f;
    if (j < JLIM) v = W[(size_t)(i*JLIM + j)*NC + n0 + c];
    tile[pr][c] = v;
  }
  __syncthreads();
  const int pp2 = (t & 31) * 2, nn = t >> 5;   // nn 0..7
  #pragma unroll
  for (int nn2 = 0; nn2 < 8; ++nn2) {
    int nrow = nn2*8 + nn;
    float v0 = tile[pp2][nrow], v1 = tile[pp2+1][nrow];
    unsigned int pk = (unsigned int)cvtpk_bf16(v0, v1);
    *(unsigned int*)((char*)Wt + ((size_t)(n0+nrow)*PLOUT + p0 + pp2)*2) = pk;
  }
}

// ---------------------------------------------------------------------------
// xuser MFMA: C[2048,256] = A[2048,48000] @ WtX^T, A[b,p'] = x[b,i]*y[b,j]
// BM=128, BN=256, 512 thr (8 waves 4Mx2N), SPLITK=16 at i-boundaries.
// Partials -> wsX[s][b][n].
// ---------------------------------------------------------------------------
__global__ __launch_bounds__(512, 2) void xuser_mfma(
    const int* __restrict__ inputs,
    const float* __restrict__ Wuf, const float* __restrict__ Wua,
    const float* __restrict__ Wfu, const float* __restrict__ Wau,
    const __hip_bfloat16* __restrict__ WtX, float* __restrict__ wsX)
{
  __shared__ __hip_bfloat16 ylds[128*168];   // [128][160 used], stride 168 (2-way banks)
  __shared__ float          xlds[128*20];    // [128][<=19 used]

  const int mb = blockIdx.x >> 4;        // 0..15
  const int s  = blockIdx.x & 15;        // K split
  const int b0 = mb * 128;
  const bool upper = s >= 8;
  const int sl  = upper ? s - 8 : s;
  const int i0l = sl * 19;
  const int cnt = (150 - i0l) < 19 ? (150 - i0l) : 19;   // 19 or 17
  const int i0  = i0l + (upper ? 150 : 0);
  const int t = threadIdx.x;

  // stage y (one half only): rows 128 x j in [0,160), zero pad j>=150
  for (int k = t; k < 128*160; k += 512) {
    int r = k / 160, j = k - r*160;
    int br = b0 + r;
    float v = 0.f;
    if (j < 150) {
      int id = upper ? inputs[br*3+2] : inputs[br*3+1];
      const float* Y = upper ? Wau : Wfu;
      v = Y[(size_t)id*150 + j];
    }
    ylds[r*168 + j] = __float2bfloat16(v);
  }
  // stage x slice: rows 128 x ii in [0,20)
  for (int k = t; k < 128*20; k += 512) {
    int r = k / 20, ii = k - r*20;
    int br = b0 + r;
    float v = 0.f;
    if (ii < cnt) {
      int u = inputs[br*3+0];
      const float* X = upper ? Wua : Wuf;
      v = X[(size_t)u*150 + i0l + ii];
    }
    xlds[r*20 + ii] = v;
  }
  __syncthreads();

  const int lane = t & 63;
  const int w  = t >> 6;
  const int mg = w >> 1;          // 0..3  (32 rows each)
  const int ng = w & 1;           // 0..1  (128 cols each)
  const int lr = lane & 15;
  const int g  = lane >> 4;

  f32x4 acc[2][8];
  #pragma unroll
  for (int i = 0; i < 2; ++i)
    #pragma unroll
    for (int j = 0; j < 8; ++j) acc[i][j] = (f32x4){0.f,0.f,0.f,0.f};

  const __hip_bfloat16* pB = WtX + (size_t)(ng*128 + lr)*48000 + (size_t)i0*160 + g*8;
  const __hip_bfloat16* yb0 = ylds + (mg*32 + lr)*168 + g*8;
  const __hip_bfloat16* yb1 = yb0 + 16*168;
  const float* xb0 = xlds + (mg*32 + lr)*20;
  const float* xb1 = xb0 + 16*20;

  for (int ii = 0; ii < cnt; ++ii) {
    float xv0 = xb0[ii];
    float xv1 = xb1[ii];
    const __hip_bfloat16* pbi = pB + ii*160;
    #pragma unroll
    for (int jj = 0; jj < 5; ++jj) {
      APack a0, a1;
      i32x4 yv0 = *(const i32x4*)(yb0 + jj*32);
      i32x4 yv1 = *(const i32x4*)(yb1 + jj*32);
      build_a(yv0, xv0, a0);
      build_a(yv1, xv1, a1);
      const __hip_bfloat16* pbj = pbi + jj*32;
      #pragma unroll
      for (int nf = 0; nf < 8; ++nf) {
        bf16x8 bv = *(const bf16x8*)(pbj + (size_t)nf*768000);  // nf*16 cols * 48000
        acc[0][nf] = mfma16(a0.v, bv, acc[0][nf]);
        acc[1][nf] = mfma16(a1.v, bv, acc[1][nf]);
      }
    }
  }

  // store partials: C/D layout (m89): reg e -> row 4*(l>>4)+e, col = l&15
  float* wp = wsX + ((size_t)s*2048 + b0)*256;
  #pragma unroll
  for (int mf = 0; mf < 2; ++mf) {
    #pragma unroll
    for (int nf = 0; nf < 8; ++nf) {
      int rb = mg*32 + mf*16 + g*4;
      int col = ng*128 + nf*16 + lr;
      f32x4 v = acc[mf][nf];
      #pragma unroll
      for (int e = 0; e < 4; ++e) wp[(size_t)(rb+e)*256 + col] = v[e];
    }
  }
}

// ---------------------------------------------------------------------------
// wuser MFMA: C[2048,128] = Aw[2048,8192] @ WtW^T, p = i*64+j. SPLITK=16.
// ---------------------------------------------------------------------------
__global__ __launch_bounds__(512, 2) void wuser_mfma(
    const int* __restrict__ inputs,
    const float* __restrict__ Wufd, const float* __restrict__ Wuad,
    const float* __restrict__ Wfud, const float* __restrict__ Waud,
    const __hip_bfloat16* __restrict__ WtW, float* __restrict__ wsW)
{
  __shared__ __hip_bfloat16 ylds[128*72];
  __shared__ float          xlds[128*9];

  const int mb = blockIdx.x >> 4;
  const int s  = blockIdx.x & 15;
  const int b0 = mb * 128;
  const bool upper = s >= 8;
  const int i0l = (s & 7) * 8;
  const int i0  = i0l + (upper ? 64 : 0);
  const int t = threadIdx.x;

  for (int k = t; k < 128*64; k += 512) {
    int r = k >> 6, j = k & 63;
    int br = b0 + r;
    int id = upper ? inputs[br*3+2] : inputs[br*3+1];
    const float* Y = upper ? Waud : Wfud;
    ylds[r*72 + j] = __float2bfloat16(Y[(size_t)id*64 + j]);
  }
  for (int k = t; k < 128*9; k += 512) {
    int r = k / 9, ii = k - r*9;
    int br = b0 + r;
    float v = 0.f;
    if (ii < 8) {
      int u = inputs[br*3+0];
      const float* X = upper ? Wuad : Wufd;
      v = X[(size_t)u*64 + i0l + ii];
    }
    xlds[r*9 + ii] = v;
  }
  __syncthreads();

  const int lane = t & 63;
  const int w  = t >> 6;
  const int mg = w >> 1;
  const int ng = w & 1;           // 0..1 (64 cols each)
  const int lr = lane & 15;
  const int g  = lane >> 4;

  f32x4 acc[2][4];
  #pragma unroll
  for (int i = 0; i < 2; ++i)
    #pragma unroll
    for (int j = 0; j < 4; ++j) acc[i][j] = (f32x4){0.f,0.f,0.f,0.f};

  const __hip_bfloat16* pB = WtW + (size_t)(ng*64 + lr)*8192 + (size_t)i0*64 + g*8;
  const __hip_bfloat16* yb0 = ylds + (mg*32 + lr)*72 + g*8;
  const __hip_bfloat16* yb1 = yb0 + 16*72;
  const float* xb0 = xlds + (mg*32 + lr)*9;
  const float* xb1 = xb0 + 16*9;

  for (int ii = 0; ii < 8; ++ii) {
    float xv0 = xb0[ii];
    float xv1 = xb1[ii];
    const __hip_bfloat16* pbi = pB + ii*64;
    #pragma unroll
    for (int jj = 0; jj < 2; ++jj) {
      APack a0, a1;
      i32x4 yv0 = *(const i32x4*)(yb0 + jj*32);
      i32x4 yv1 = *(const i32x4*)(yb1 + jj*32);
      build_a(yv0, xv0, a0);
      build_a(yv1, xv1, a1);
      const __hip_bfloat16* pbj = pbi + jj*32;
      #pragma unroll
      for (int nf = 0; nf < 4; ++nf) {
        bf16x8 bv = *(const bf16x8*)(pbj + (size_t)nf*131072);  // nf*16 cols * 8192
        acc[0][nf] = mfma16(a0.v, bv, acc[0][nf]);
        acc[1][nf] = mfma16(a1.v, bv, acc[1][nf]);
      }
    }
  }

  float* wp = wsW + ((size_t)s*2048 + b0)*128;
  #pragma unroll
  for (int mf = 0; mf < 2; ++mf) {
    #pragma unroll
    for (int nf = 0; nf < 4; ++nf) {
      int rb = mg*32 + mf*16 + g*4;
      int col = ng*64 + nf*16 + lr;
      f32x4 v = acc[mf][nf];
      #pragma unroll
      for (int e = 0; e < 4; ++e) wp[(size_t)(rb+e)*128 + col] = v[e];
    }
  }
}

// ---------------------------------------------------------------------------
// Epilogue: sum partials + bias + relu -> expert rows.
// ---------------------------------------------------------------------------
__global__ __launch_bounds__(256) void epilogue_kernel(
    const float* __restrict__ wsX, const float* __restrict__ wsW,
    const float* __restrict__ b256, const float* __restrict__ b128,
    float* __restrict__ out)
{
  int idx = blockIdx.x*256 + threadIdx.x;
  if (idx >= BB*384) return;
  int b = idx / 384, c = idx - b*384;
  if (c < 256) {
    float acc = b256[c];
    #pragma unroll
    for (int k = 0; k < 16; ++k) acc += wsX[((size_t)k*BB + b)*256 + c];
    out[(size_t)b*EXPERT_W + X_OFF + c] = acc > 0.f ? acc : 0.f;
  } else {
    int cc = c - 256;
    float acc = b128[cc];
    #pragma unroll
    for (int k = 0; k < 16; ++k) acc += wsW[((size_t)k*BB + b)*128 + cc];
    out[(size_t)b*EXPERT_W + W_OFF + cc] = acc > 0.f ? acc : 0.f;
  }
}

// ---------------------------------------------------------------------------
// Fallback VALU kernels (round-2, verified-passing) used if ws too small.
// ---------------------------------------------------------------------------
static constexpr int NPAIR_X = 300 * 150;
static constexpr int CHX     = 128;

__global__ __launch_bounds__(256) void xuser_kernel(
    const int* __restrict__ inputs,
    const float* __restrict__ Wuf, const float* __restrict__ Wua,
    const float* __restrict__ Wfu, const float* __restrict__ Wau,
    const float* __restrict__ W256, const float* __restrict__ b256,
    float* __restrict__ out)
{
    __shared__ float xs[16][308];
    __shared__ float ys[16][308];
    __shared__ float xy[CHX][16];
    const int half = blockIdx.x & 1;
    const int bg   = blockIdx.x >> 1;
    const int b0   = bg * 16;
    const int t    = threadIdx.x;
    const int bl   = t & 15;
    const int kg   = t >> 4;
    const int kbase = half * 128 + kg * 8;
    for (int idx = t; idx < 16 * DD; idx += 256) {
        int bb = idx / DD;
        int c  = idx - bb * DD;
        int u = inputs[(b0+bb)*3 + 0];
        int f = inputs[(b0+bb)*3 + 1];
        int a = inputs[(b0+bb)*3 + 2];
        xs[bb][c]       = Wuf[u*DD + c];
        xs[bb][150 + c] = Wua[u*DD + c];
        ys[bb][c]       = Wfu[f*DD + c];
        ys[bb][150 + c] = Wau[a*DD + c];
    }
    float acc[8] = {0,0,0,0,0,0,0,0};
    for (int base = 0; base < NPAIR_X; base += CHX) {
        __syncthreads();
        #pragma unroll
        for (int r = 0; r < (CHX*16)/256; ++r) {
            int idx = t + r * 256;
            int pl  = idx >> 4;
            int bb  = idx & 15;
            int p   = base + pl;
            if (p < NPAIR_X) {
                int i = p / 150;
                int j = p - i * 150;
                xy[pl][bb] = xs[bb][i] * ys[bb][(i >= 150 ? 150 : 0) + j];
            }
        }
        __syncthreads();
        const int lim = min(CHX, NPAIR_X - base);
        const float* wp = W256 + base * 256 + kbase;
        for (int pl = 0; pl < lim; ++pl) {
            float sv = xy[pl][bl];
            const float4* w4 = (const float4*)(wp + pl * 256);
            float4 w0 = w4[0], w1 = w4[1];
            acc[0] = fmaf(sv, w0.x, acc[0]); acc[1] = fmaf(sv, w0.y, acc[1]);
            acc[2] = fmaf(sv, w0.z, acc[2]); acc[3] = fmaf(sv, w0.w, acc[3]);
            acc[4] = fmaf(sv, w1.x, acc[4]); acc[5] = fmaf(sv, w1.y, acc[5]);
            acc[6] = fmaf(sv, w1.z, acc[6]); acc[7] = fmaf(sv, w1.w, acc[7]);
        }
    }
    const int rowbase = (b0 + bl) * EXPERT_W + X_OFF;
    #pragma unroll
    for (int m = 0; m < 8; ++m) {
        float v = acc[m] + b256[kbase + m];
        out[rowbase + kbase + m] = (v > 0.f ? v : 0.f);
    }
}

static constexpr int NPAIR_W = 128 * 64;
static constexpr int CHW     = 256;

__global__ __launch_bounds__(256) void wuser_kernel(
    const int* __restrict__ inputs,
    const float* __restrict__ Wufd, const float* __restrict__ Wuad,
    const float* __restrict__ Wfud, const float* __restrict__ Waud,
    const float* __restrict__ W128, const float* __restrict__ b128,
    float* __restrict__ out)
{
    __shared__ float xs[8][132];
    __shared__ float ys[8][132];
    __shared__ float xy[CHW][8];
    const int bg = blockIdx.x;
    const int b0 = bg * 8;
    const int t  = threadIdx.x;
    const int bl = t & 7;
    const int kg = t >> 3;
    const int kbase = kg * 4;
    for (int idx = t; idx < 8 * DKK; idx += 256) {
        int bb = idx >> 6;
        int c  = idx & 63;
        int u = inputs[(b0+bb)*3 + 0];
        int f = inputs[(b0+bb)*3 + 1];
        int a = inputs[(b0+bb)*3 + 2];
        xs[bb][c]      = Wufd[u*DKK + c];
        xs[bb][64 + c] = Wuad[u*DKK + c];
        ys[bb][c]      = Wfud[f*DKK + c];
        ys[bb][64 + c] = Waud[a*DKK + c];
    }
    float acc[4] = {0,0,0,0};
    for (int base = 0; base < NPAIR_W; base += CHW) {
        __syncthreads();
        #pragma unroll
        for (int r = 0; r < (CHW*8)/256; ++r) {
            int idx = t + r * 256;
            int pl  = idx >> 3;
            int bb  = idx & 7;
            int p   = base + pl;
            int i = p >> 6;
            int j = p & 63;
            xy[pl][bb] = xs[bb][i] * ys[bb][(i >= 64 ? 64 : 0) + j];
        }
        __syncthreads();
        const float* wp = W128 + base * 128 + kbase;
        for (int pl = 0; pl < CHW; ++pl) {
            float sv = xy[pl][bl];
            float4 wv = *(const float4*)(wp + pl * 128);
            acc[0] = fmaf(sv, wv.x, acc[0]); acc[1] = fmaf(sv, wv.y, acc[1]);
            acc[2] = fmaf(sv, wv.z, acc[2]); acc[3] = fmaf(sv, wv.w, acc[3]);
        }
    }
    const int rowbase = (b0 + bl) * EXPERT_W + W_OFF;
    #pragma unroll
    for (int m = 0; m < 4; ++m) {
        float v = acc[m] + b128[kbase + m];
        out[rowbase + kbase + m] = (v > 0.f ? v : 0.f);
    }
}

// ---------------------------------------------------------------------------
extern "C" void kernel_launch(void* const* d_in, const int* in_sizes, int n_in,
                              void* d_out, int out_size, void* d_ws, size_t ws_size,
                              hipStream_t stream)
{
    const int*   inputs = (const int*)  d_in[0];
    const int*   shifts = (const int*)  d_in[1];
    const float* Wuf    = (const float*)d_in[2];
    const float* Wfu    = (const float*)d_in[3];
    const float* Wua    = (const float*)d_in[4];
    const float* Wau    = (const float*)d_in[5];
    const float* Wfe    = (const float*)d_in[6];
    const float* Wut    = (const float*)d_in[7];
    const float* Wuk1   = (const float*)d_in[8];
    const float* Wuk2   = (const float*)d_in[9];
    const float* Wft    = (const float*)d_in[10];
    const float* Wfk1   = (const float*)d_in[11];
    const float* Wfk2   = (const float*)d_in[12];
    const float* Wufd   = (const float*)d_in[13];
    const float* Wfud   = (const float*)d_in[14];
    const float* Wuad   = (const float*)d_in[15];
    const float* Waud   = (const float*)d_in[16];
    const float* W256   = (const float*)d_in[17];
    const float* b256   = (const float*)d_in[18];
    const float* W128   = (const float*)d_in[19];
    const float* b128   = (const float*)d_in[20];

    float* out = (float*)d_out;

    gather_kernel<<<BB, 256, 0, stream>>>(inputs, shifts,
        Wuf, Wfu, Wua, Wau, Wfe, Wut, Wuk1, Wuk2, Wft, Wfk1, Wfk2,
        Wufd, Wfud, Wuad, Waud, out);

    if (ws_size >= WS_NEED) {
        char* ws = (char*)d_ws;
        __hip_bfloat16* WtX = (__hip_bfloat16*)(ws + WTX_OFF);
        __hip_bfloat16* WtW = (__hip_bfloat16*)(ws + WTW_OFF);
        float* wsX = (float*)(ws + WSX_OFF);
        float* wsW = (float*)(ws + WSW_OFF);

        // W256 [45000][256] -> WtX [256][48000] bf16 (padded)
        transpose_kernel<256, 48000, 160, 150><<<750*4, 256, 0, stream>>>(W256, WtX);
        // W128 [8192][128]  -> WtW [128][8192] bf16
        transpose_kernel<128, 8192, 64, 64><<<128*2, 256, 0, stream>>>(W128, WtW);

        xuser_mfma<<<256, 512, 0, stream>>>(inputs, Wuf, Wua, Wfu, Wau, WtX, wsX);
        wuser_mfma<<<256, 512, 0, stream>>>(inputs, Wufd, Wuad, Wfud, Waud, WtW, wsW);

        epilogue_kernel<<<(BB*384 + 255)/256, 256, 0, stream>>>(wsX, wsW, b256, b128, out);
    } else {
        xuser_kernel<<<256, 256, 0, stream>>>(inputs, Wuf, Wua, Wfu, Wau, W256, b256, out);
        wuser_kernel<<<256, 256, 0, stream>>>(inputs, Wufd, Wuad, Wfud, Waud, W128, b128, out);
    }
}

// Round 4
// 155.700 us; speedup vs baseline: 20.1058x; 1.8397x over previous
//
#include <hip/hip_runtime.h>
#include <hip/hip_bf16.h>
#include <stdint.h>

#define BB   2048
#define DD   150
#define DKK  64

static constexpr int EXPERT_W  = 1774;        // 5*150 + 10*64 + 256 + 128
static constexpr int X_OFF     = 1390;
static constexpr int W_OFF     = 1646;
static constexpr int EXPERT_SZ = BB * EXPERT_W;
static constexpr int OH_BASE   = EXPERT_SZ;
static constexpr int FM_BASE   = OH_BASE + BB * 3;

// ---- workspace layout (bytes) ----
static constexpr size_t WTX_OFF = 0;               // bf16 [256][48000]  (p' = i*160+j, zero pad j>=150)
static constexpr size_t WTW_OFF = 24576000;        // bf16 [128][8192]
static constexpr size_t WSX_OFF = 26673152;        // f32  [16][2048][256] partials
static constexpr size_t WSW_OFF = 60227584;        // f32  [16][2048][128] partials
static constexpr size_t WS_NEED = 77004800;

typedef __attribute__((ext_vector_type(8))) short bf16x8;
typedef __attribute__((ext_vector_type(4))) float f32x4;

union APack { int d[4]; bf16x8 v; };

__device__ __forceinline__ int cvtpk_bf16(float a, float b) {
  int r; asm("v_cvt_pk_bf16_f32 %0, %1, %2" : "=v"(r) : "v"(a), "v"(b)); return r;
}
__device__ __forceinline__ f32x4 mfma16(bf16x8 a, bf16x8 b, f32x4 c) {
  return __builtin_amdgcn_mfma_f32_16x16x32_bf16(a, b, c, 0, 0, 0);
}
// async global->LDS, 16B per lane; l must be the wave-uniform base (lane writes l + lane*16)
__device__ __forceinline__ void gload16(const void* g, void* l) {
  __builtin_amdgcn_global_load_lds(
      (__attribute__((address_space(1))) void*)(g),
      (__attribute__((address_space(3))) void*)(l), 16, 0, 0);
}

// ---------------------------------------------------------------------------
// Kernel 1: gathers -> expert row segments, one_hot, fm copies (f32 out).
// ---------------------------------------------------------------------------
__global__ __launch_bounds__(256) void gather_kernel(
    const int* __restrict__ inputs, const int* __restrict__ shifts,
    const float* __restrict__ Wuf, const float* __restrict__ Wfu,
    const float* __restrict__ Wua, const float* __restrict__ Wau,
    const float* __restrict__ Wfe,
    const float* __restrict__ Wut, const float* __restrict__ Wuk1, const float* __restrict__ Wuk2,
    const float* __restrict__ Wft, const float* __restrict__ Wfk1, const float* __restrict__ Wfk2,
    const float* __restrict__ Wufd, const float* __restrict__ Wfud,
    const float* __restrict__ Wuad, const float* __restrict__ Waud,
    float* __restrict__ out)
{
    const int b = blockIdx.x;
    const int u = inputs[b*3 + 0];
    const int f = inputs[b*3 + 1];
    const int a = inputs[b*3 + 2];
    float* row = out + b * EXPERT_W;
    float* fm  = out + FM_BASE;
    const int t = threadIdx.x;

    for (int c = t; c < DD; c += 256) {
        float ufe = Wuf[u*DD + c];
        float uae = Wua[u*DD + c];
        float fue = Wfu[f*DD + c];
        float fee = Wfe[f*DD + c];
        float aue = Wau[a*DD + c];
        row[0    + c] = ufe;
        row[150  + c] = uae;
        row[620  + c] = fue;
        row[898  + c] = fee;
        row[1176 + c] = aue;
        fm[0*BB*DD + b*DD + c] = ufe;
        fm[1*BB*DD + b*DD + c] = uae;
        fm[2*BB*DD + b*DD + c] = fue;
        fm[3*BB*DD + b*DD + c] = aue;
    }
    for (int c = t; c < DKK; c += 256) {
        row[300  + c] = Wut [u*DKK + c];
        row[364  + c] = Wuk1[u*DKK + c];
        row[428  + c] = Wuk2[u*DKK + c];
        row[492  + c] = Wufd[u*DKK + c];
        row[556  + c] = Wuad[u*DKK + c];
        row[770  + c] = Wft [f*DKK + c];
        row[834  + c] = Wfk1[f*DKK + c];
        row[1048 + c] = Wfk2[f*DKK + c];
        row[1112 + c] = Wfud[f*DKK + c];
        row[1326 + c] = Waud[a*DKK + c];
    }
    if (t < 3) {
        out[OH_BASE + b*3 + t] = (float)(inputs[b*3 + t] + shifts[t]);
    }
}

// ---------------------------------------------------------------------------
// Transpose + bf16 cast:  W[p][n] f32  ->  Wt[n][p'] bf16, p' = i*JDIV + j,
// source p = i*JLIM + j, zero for j >= JLIM. 64x64 tiles.
// ---------------------------------------------------------------------------
template<int NC, int PLOUT, int JDIV, int JLIM>
__global__ __launch_bounds__(256) void transpose_kernel(
    const float* __restrict__ W, __hip_bfloat16* __restrict__ Wt)
{
  __shared__ float tile[64][69];
  const int ntn = NC / 64;
  const int bp = blockIdx.x / ntn;
  const int bn = blockIdx.x - bp * ntn;
  const int p0 = bp * 64, n0 = bn * 64;
  const int t = threadIdx.x;
  const int c = t & 63, r4 = t >> 6;
  #pragma unroll 4
  for (int rr = 0; rr < 16; ++rr) {
    int pr = rr*4 + r4;
    int pp = p0 + pr;
    int i = pp / JDIV, j = pp - i * JDIV;
    float v = 0.f;
    if (j < JLIM) v = W[(size_t)(i*JLIM + j)*NC + n0 + c];
    tile[pr][c] = v;
  }
  __syncthreads();
  const int pp2 = (t & 31) * 2, nn = t >> 5;
  #pragma unroll
  for (int nn2 = 0; nn2 < 8; ++nn2) {
    int nrow = nn2*8 + nn;
    float v0 = tile[pp2][nrow], v1 = tile[pp2+1][nrow];
    unsigned int pk = (unsigned int)cvtpk_bf16(v0, v1);
    *(unsigned int*)((char*)Wt + ((size_t)(n0+nrow)*PLOUT + p0 + pp2)*2) = pk;
  }
}

// ---------------------------------------------------------------------------
// xuser MFMA v3 (m97-style): C[2048,256] = A @ WtX^T, A[b, i*160+j] = x[b,i]*y[b,j]
// BM=128, BN=256, 512 thr = 8 waves (2 mg x 4 ng); each wave 4 m-frags x 4 n-frags.
// B double-buffered in LDS via global_load_lds; y in registers per jj; x in LDS.
// SPLITK=16 (s = blockIdx & 15 -> XCD = s%8 keeps K-slices XCD-L2-resident).
// ---------------------------------------------------------------------------
__global__ __launch_bounds__(512, 1) void xuser_mfma(
    const int* __restrict__ inputs,
    const float* __restrict__ Wuf, const float* __restrict__ Wua,
    const float* __restrict__ Wfu, const float* __restrict__ Wau,
    const __hip_bfloat16* __restrict__ WtX, float* __restrict__ wsX)
{
  __shared__ float xlds[128*20];               // 10 KB  [row][ii]
  __shared__ __hip_bfloat16 blds[2][8192];     // 2 x 16 KB, subtile [blk16n][4ksub][16n][8k]

  const int mb = blockIdx.x >> 4;
  const int s  = blockIdx.x & 15;
  const int b0 = mb * 128;
  const bool upper = s >= 8;
  const int sl  = upper ? s - 8 : s;
  const int i0l = sl * 19;
  const int cnt = (150 - i0l) < 19 ? (150 - i0l) : 19;   // 19 or 17
  const int i0  = i0l + (upper ? 150 : 0);
  const int tid = threadIdx.x;

  const float* X = upper ? Wua : Wuf;
  const float* Y = upper ? Wau : Wfu;
  const int yoff = upper ? 2 : 1;

  // stage x [128][20]
  for (int k = tid; k < 128*20; k += 512) {
    int r = k / 20, ii = k - r*20;
    float v = 0.f;
    if (ii < cnt) {
      int u = inputs[(b0+r)*3];
      v = X[(size_t)u*150 + i0l + ii];
    }
    xlds[k] = v;
  }

  const int lane = tid & 63;
  const int w  = tid >> 6;
  const int mg = w >> 2;        // 0..1 (64 rows)
  const int ng = w & 3;         // 0..3 (64 cols)
  const int lr = lane & 15;
  const int g  = lane >> 4;

  // per-lane y row ids
  int yid[4];
  #pragma unroll
  for (int mf = 0; mf < 4; ++mf)
    yid[mf] = inputs[(size_t)(b0 + mg*64 + mf*16 + lr)*3 + yoff];

  // staging per-thread source offsets (q = 0,1 -> 2 x 8KB halves)
  size_t srcoff[2];
  #pragma unroll
  for (int q = 0; q < 2; ++q) {
    int slot = q*512 + tid;
    int blk = slot >> 6, ww = slot & 63;
    int ksub = ww >> 4, nloc = ww & 15;
    int n = blk*16 + nloc;
    srcoff[q] = (size_t)n*48000 + (size_t)(ksub*8);
  }
  const size_t wavebytes = (size_t)((tid >> 6) << 6) * 16;   // wave slot base * 16B

  f32x4 acc[4][4];
  #pragma unroll
  for (int i = 0; i < 4; ++i)
    #pragma unroll
    for (int j = 0; j < 4; ++j) acc[i][j] = (f32x4){0.f,0.f,0.f,0.f};

  // prologue: stage chunk (jj=0, ii=0)
  {
    int kb = i0*160;
    #pragma unroll
    for (int q = 0; q < 2; ++q)
      gload16(WtX + srcoff[q] + kb, (char*)&blds[0][0] + (size_t)q*8192 + wavebytes);
  }
  __syncthreads();

  int buf = 0;
  for (int jj = 0; jj < 5; ++jj) {
    // y fragments for this jj (loop-invariant over ii); clamp keeps loads near row end
    float yreg[4][8];
    int jb = jj*32 + g*8; if (jb > 142) jb = 142;   // pad region hits zero W rows anyway
    #pragma unroll
    for (int mf = 0; mf < 4; ++mf) {
      const float* yp = Y + (size_t)yid[mf]*150 + jb;
      #pragma unroll
      for (int h = 0; h < 4; ++h) {
        float2 v = *(const float2*)(yp + h*2);
        yreg[mf][h*2]   = v.x;
        yreg[mf][h*2+1] = v.y;
      }
    }
    for (int ii = 0; ii < cnt; ++ii) {
      // prefetch next chunk into other buffer (overlaps this chunk's compute)
      int njj = jj, nii = ii + 1;
      if (nii == cnt) { njj++; nii = 0; }
      if (njj < 5) {
        int kb = (i0 + nii)*160 + njj*32;
        #pragma unroll
        for (int q = 0; q < 2; ++q)
          gload16(WtX + srcoff[q] + kb, (char*)&blds[buf^1][0] + (size_t)q*8192 + wavebytes);
      }
      // consume current buffer
      const __hip_bfloat16* bb = &blds[buf][0];
      bf16x8 bv[4];
      #pragma unroll
      for (int nf = 0; nf < 4; ++nf)
        bv[nf] = *(const bf16x8*)(bb + ((ng*4+nf)*512 + g*128 + lr*8));
      APack a[4];
      #pragma unroll
      for (int mf = 0; mf < 4; ++mf) {
        float xv = xlds[(mg*64 + mf*16 + lr)*20 + ii];
        #pragma unroll
        for (int e = 0; e < 4; ++e)
          a[mf].d[e] = cvtpk_bf16(xv*yreg[mf][2*e], xv*yreg[mf][2*e+1]);
      }
      #pragma unroll
      for (int mf = 0; mf < 4; ++mf)
        #pragma unroll
        for (int nf = 0; nf < 4; ++nf)
          acc[mf][nf] = mfma16(a[mf].v, bv[nf], acc[mf][nf]);
      __syncthreads();
      buf ^= 1;
    }
  }

  // store partials: C/D layout: col = lane&15, row = 4*(lane>>4)+e
  float* wp = wsX + ((size_t)s*2048 + b0)*256;
  #pragma unroll
  for (int mf = 0; mf < 4; ++mf) {
    #pragma unroll
    for (int nf = 0; nf < 4; ++nf) {
      int rb  = mg*64 + mf*16 + g*4;
      int col = ng*64 + nf*16 + lr;
      f32x4 v = acc[mf][nf];
      #pragma unroll
      for (int e = 0; e < 4; ++e) wp[(size_t)(rb+e)*256 + col] = v[e];
    }
  }
}

// ---------------------------------------------------------------------------
// wuser MFMA v3: C[2048,128] = Aw @ WtW^T, p = i*64+j. BM=128, BN=128.
// 8 waves (2 mg x 4 ng); wave = 4 m-frags x 2 n-frags. SPLITK=16.
// ---------------------------------------------------------------------------
__global__ __launch_bounds__(512, 1) void wuser_mfma(
    const int* __restrict__ inputs,
    const float* __restrict__ Wufd, const float* __restrict__ Wuad,
    const float* __restrict__ Wfud, const float* __restrict__ Waud,
    const __hip_bfloat16* __restrict__ WtW, float* __restrict__ wsW)
{
  __shared__ float xlds[128*8];                // 4 KB
  __shared__ __hip_bfloat16 blds[2][4096];     // 2 x 8 KB

  const int mb = blockIdx.x >> 4;
  const int s  = blockIdx.x & 15;
  const int b0 = mb * 128;
  const bool upper = s >= 8;
  const int i0l = (s & 7) * 8;
  const int i0  = i0l + (upper ? 64 : 0);
  const int tid = threadIdx.x;

  const float* X = upper ? Wuad : Wufd;
  const float* Y = upper ? Waud : Wfud;
  const int yoff = upper ? 2 : 1;

  for (int k = tid; k < 128*8; k += 512) {
    int r = k >> 3, ii = k & 7;
    int u = inputs[(size_t)(b0+r)*3];
    xlds[k] = X[(size_t)u*64 + i0l + ii];
  }

  const int lane = tid & 63;
  const int w  = tid >> 6;
  const int mg = w >> 2;
  const int ng = w & 3;         // 0..3 (32 cols)
  const int lr = lane & 15;
  const int g  = lane >> 4;

  int yid[4];
  #pragma unroll
  for (int mf = 0; mf < 4; ++mf)
    yid[mf] = inputs[(size_t)(b0 + mg*64 + mf*16 + lr)*3 + yoff];

  // one 16B issue per thread per chunk (8KB)
  const int blk = tid >> 6, ww = tid & 63;
  const int ksub = ww >> 4, nloc = ww & 15;
  const size_t srcoff = (size_t)(blk*16 + nloc)*8192 + (size_t)(ksub*8);
  const size_t wavebytes = (size_t)((tid >> 6) << 6) * 16;

  f32x4 acc[4][2];
  #pragma unroll
  for (int i = 0; i < 4; ++i)
    #pragma unroll
    for (int j = 0; j < 2; ++j) acc[i][j] = (f32x4){0.f,0.f,0.f,0.f};

  {
    int kb = i0*64;
    gload16(WtW + srcoff + kb, (char*)&blds[0][0] + wavebytes);
  }
  __syncthreads();

  int buf = 0;
  for (int jj = 0; jj < 2; ++jj) {
    float yreg[4][8];
    int jb = jj*32 + g*8;
    #pragma unroll
    for (int mf = 0; mf < 4; ++mf) {
      const float* yp = Y + (size_t)yid[mf]*64 + jb;
      #pragma unroll
      for (int h = 0; h < 2; ++h) {
        float4 v = *(const float4*)(yp + h*4);
        yreg[mf][h*4]   = v.x;
        yreg[mf][h*4+1] = v.y;
        yreg[mf][h*4+2] = v.z;
        yreg[mf][h*4+3] = v.w;
      }
    }
    for (int ii = 0; ii < 8; ++ii) {
      int njj = jj, nii = ii + 1;
      if (nii == 8) { njj++; nii = 0; }
      if (njj < 2) {
        int kb = (i0 + nii)*64 + njj*32;
        gload16(WtW + srcoff + kb, (char*)&blds[buf^1][0] + wavebytes);
      }
      const __hip_bfloat16* bb = &blds[buf][0];
      bf16x8 bv[2];
      #pragma unroll
      for (int nf = 0; nf < 2; ++nf)
        bv[nf] = *(const bf16x8*)(bb + ((ng*2+nf)*512 + g*128 + lr*8));
      APack a[4];
      #pragma unroll
      for (int mf = 0; mf < 4; ++mf) {
        float xv = xlds[(mg*64 + mf*16 + lr)*8 + ii];
        #pragma unroll
        for (int e = 0; e < 4; ++e)
          a[mf].d[e] = cvtpk_bf16(xv*yreg[mf][2*e], xv*yreg[mf][2*e+1]);
      }
      #pragma unroll
      for (int mf = 0; mf < 4; ++mf)
        #pragma unroll
        for (int nf = 0; nf < 2; ++nf)
          acc[mf][nf] = mfma16(a[mf].v, bv[nf], acc[mf][nf]);
      __syncthreads();
      buf ^= 1;
    }
  }

  float* wp = wsW + ((size_t)s*2048 + b0)*128;
  #pragma unroll
  for (int mf = 0; mf < 4; ++mf) {
    #pragma unroll
    for (int nf = 0; nf < 2; ++nf) {
      int rb  = mg*64 + mf*16 + g*4;
      int col = ng*32 + nf*16 + lr;
      f32x4 v = acc[mf][nf];
      #pragma unroll
      for (int e = 0; e < 4; ++e) wp[(size_t)(rb+e)*128 + col] = v[e];
    }
  }
}

// ---------------------------------------------------------------------------
// Epilogue: sum partials + bias + relu -> expert rows.
// ---------------------------------------------------------------------------
__global__ __launch_bounds__(256) void epilogue_kernel(
    const float* __restrict__ wsX, const float* __restrict__ wsW,
    const float* __restrict__ b256, const float* __restrict__ b128,
    float* __restrict__ out)
{
  int idx = blockIdx.x*256 + threadIdx.x;
  if (idx >= BB*384) return;
  int b = idx / 384, c = idx - b*384;
  if (c < 256) {
    float acc = b256[c];
    #pragma unroll
    for (int k = 0; k < 16; ++k) acc += wsX[((size_t)k*BB + b)*256 + c];
    out[(size_t)b*EXPERT_W + X_OFF + c] = acc > 0.f ? acc : 0.f;
  } else {
    int cc = c - 256;
    float acc = b128[cc];
    #pragma unroll
    for (int k = 0; k < 16; ++k) acc += wsW[((size_t)k*BB + b)*128 + cc];
    out[(size_t)b*EXPERT_W + W_OFF + cc] = acc > 0.f ? acc : 0.f;
  }
}

// ---------------------------------------------------------------------------
// Fallback VALU kernels (round-2, verified-passing) used if ws too small.
// ---------------------------------------------------------------------------
static constexpr int NPAIR_X = 300 * 150;
static constexpr int CHX     = 128;

__global__ __launch_bounds__(256) void xuser_kernel(
    const int* __restrict__ inputs,
    const float* __restrict__ Wuf, const float* __restrict__ Wua,
    const float* __restrict__ Wfu, const float* __restrict__ Wau,
    const float* __restrict__ W256, const float* __restrict__ b256,
    float* __restrict__ out)
{
    __shared__ float xs[16][308];
    __shared__ float ys[16][308];
    __shared__ float xy[CHX][16];
    const int half = blockIdx.x & 1;
    const int bg   = blockIdx.x >> 1;
    const int b0   = bg * 16;
    const int t    = threadIdx.x;
    const int bl   = t & 15;
    const int kg   = t >> 4;
    const int kbase = half * 128 + kg * 8;
    for (int idx = t; idx < 16 * DD; idx += 256) {
        int bb = idx / DD;
        int c  = idx - bb * DD;
        int u = inputs[(b0+bb)*3 + 0];
        int f = inputs[(b0+bb)*3 + 1];
        int a = inputs[(b0+bb)*3 + 2];
        xs[bb][c]       = Wuf[u*DD + c];
        xs[bb][150 + c] = Wua[u*DD + c];
        ys[bb][c]       = Wfu[f*DD + c];
        ys[bb][150 + c] = Wau[a*DD + c];
    }
    float acc[8] = {0,0,0,0,0,0,0,0};
    for (int base = 0; base < NPAIR_X; base += CHX) {
        __syncthreads();
        #pragma unroll
        for (int r = 0; r < (CHX*16)/256; ++r) {
            int idx = t + r * 256;
            int pl  = idx >> 4;
            int bb  = idx & 15;
            int p   = base + pl;
            if (p < NPAIR_X) {
                int i = p / 150;
                int j = p - i * 150;
                xy[pl][bb] = xs[bb][i] * ys[bb][(i >= 150 ? 150 : 0) + j];
            }
        }
        __syncthreads();
        const int lim = min(CHX, NPAIR_X - base);
        const float* wp = W256 + base * 256 + kbase;
        for (int pl = 0; pl < lim; ++pl) {
            float sv = xy[pl][bl];
            const float4* w4 = (const float4*)(wp + pl * 256);
            float4 w0 = w4[0], w1 = w4[1];
            acc[0] = fmaf(sv, w0.x, acc[0]); acc[1] = fmaf(sv, w0.y, acc[1]);
            acc[2] = fmaf(sv, w0.z, acc[2]); acc[3] = fmaf(sv, w0.w, acc[3]);
            acc[4] = fmaf(sv, w1.x, acc[4]); acc[5] = fmaf(sv, w1.y, acc[5]);
            acc[6] = fmaf(sv, w1.z, acc[6]); acc[7] = fmaf(sv, w1.w, acc[7]);
        }
    }
    const int rowbase = (b0 + bl) * EXPERT_W + X_OFF;
    #pragma unroll
    for (int m = 0; m < 8; ++m) {
        float v = acc[m] + b256[kbase + m];
        out[rowbase + kbase + m] = (v > 0.f ? v : 0.f);
    }
}

static constexpr int NPAIR_W = 128 * 64;
static constexpr int CHW     = 256;

__global__ __launch_bounds__(256) void wuser_kernel(
    const int* __restrict__ inputs,
    const float* __restrict__ Wufd, const float* __restrict__ Wuad,
    const float* __restrict__ Wfud, const float* __restrict__ Waud,
    const float* __restrict__ W128, const float* __restrict__ b128,
    float* __restrict__ out)
{
    __shared__ float xs[8][132];
    __shared__ float ys[8][132];
    __shared__ float xy[CHW][8];
    const int bg = blockIdx.x;
    const int b0 = bg * 8;
    const int t  = threadIdx.x;
    const int bl = t & 7;
    const int kg = t >> 3;
    const int kbase = kg * 4;
    for (int idx = t; idx < 8 * DKK; idx += 256) {
        int bb = idx >> 6;
        int c  = idx & 63;
        int u = inputs[(b0+bb)*3 + 0];
        int f = inputs[(b0+bb)*3 + 1];
        int a = inputs[(b0+bb)*3 + 2];
        xs[bb][c]      = Wufd[u*DKK + c];
        xs[bb][64 + c] = Wuad[u*DKK + c];
        ys[bb][c]      = Wfud[f*DKK + c];
        ys[bb][64 + c] = Waud[a*DKK + c];
    }
    float acc[4] = {0,0,0,0};
    for (int base = 0; base < NPAIR_W; base += CHW) {
        __syncthreads();
        #pragma unroll
        for (int r = 0; r < (CHW*8)/256; ++r) {
            int idx = t + r * 256;
            int pl  = idx >> 3;
            int bb  = idx & 7;
            int p   = base + pl;
            int i = p >> 6;
            int j = p & 63;
            xy[pl][bb] = xs[bb][i] * ys[bb][(i >= 64 ? 64 : 0) + j];
        }
        __syncthreads();
        const float* wp = W128 + base * 128 + kbase;
        for (int pl = 0; pl < CHW; ++pl) {
            float sv = xy[pl][bl];
            float4 wv = *(const float4*)(wp + pl * 128);
            acc[0] = fmaf(sv, wv.x, acc[0]); acc[1] = fmaf(sv, wv.y, acc[1]);
            acc[2] = fmaf(sv, wv.z, acc[2]); acc[3] = fmaf(sv, wv.w, acc[3]);
        }
    }
    const int rowbase = (b0 + bl) * EXPERT_W + W_OFF;
    #pragma unroll
    for (int m = 0; m < 4; ++m) {
        float v = acc[m] + b128[kbase + m];
        out[rowbase + kbase + m] = (v > 0.f ? v : 0.f);
    }
}

// ---------------------------------------------------------------------------
extern "C" void kernel_launch(void* const* d_in, const int* in_sizes, int n_in,
                              void* d_out, int out_size, void* d_ws, size_t ws_size,
                              hipStream_t stream)
{
    const int*   inputs = (const int*)  d_in[0];
    const int*   shifts = (const int*)  d_in[1];
    const float* Wuf    = (const float*)d_in[2];
    const float* Wfu    = (const float*)d_in[3];
    const float* Wua    = (const float*)d_in[4];
    const float* Wau    = (const float*)d_in[5];
    const float* Wfe    = (const float*)d_in[6];
    const float* Wut    = (const float*)d_in[7];
    const float* Wuk1   = (const float*)d_in[8];
    const float* Wuk2   = (const float*)d_in[9];
    const float* Wft    = (const float*)d_in[10];
    const float* Wfk1   = (const float*)d_in[11];
    const float* Wfk2   = (const float*)d_in[12];
    const float* Wufd   = (const float*)d_in[13];
    const float* Wfud   = (const float*)d_in[14];
    const float* Wuad   = (const float*)d_in[15];
    const float* Waud   = (const float*)d_in[16];
    const float* W256   = (const float*)d_in[17];
    const float* b256   = (const float*)d_in[18];
    const float* W128   = (const float*)d_in[19];
    const float* b128   = (const float*)d_in[20];

    float* out = (float*)d_out;

    gather_kernel<<<BB, 256, 0, stream>>>(inputs, shifts,
        Wuf, Wfu, Wua, Wau, Wfe, Wut, Wuk1, Wuk2, Wft, Wfk1, Wfk2,
        Wufd, Wfud, Wuad, Waud, out);

    if (ws_size >= WS_NEED) {
        char* ws = (char*)d_ws;
        __hip_bfloat16* WtX = (__hip_bfloat16*)(ws + WTX_OFF);
        __hip_bfloat16* WtW = (__hip_bfloat16*)(ws + WTW_OFF);
        float* wsX = (float*)(ws + WSX_OFF);
        float* wsW = (float*)(ws + WSW_OFF);

        transpose_kernel<256, 48000, 160, 150><<<750*4, 256, 0, stream>>>(W256, WtX);
        transpose_kernel<128, 8192, 64, 64><<<128*2, 256, 0, stream>>>(W128, WtW);

        xuser_mfma<<<256, 512, 0, stream>>>(inputs, Wuf, Wua, Wfu, Wau, WtX, wsX);
        wuser_mfma<<<256, 512, 0, stream>>>(inputs, Wufd, Wuad, Wfud, Waud, WtW, wsW);

        epilogue_kernel<<<(BB*384 + 255)/256, 256, 0, stream>>>(wsX, wsW, b256, b128, out);
    } else {
        xuser_kernel<<<256, 256, 0, stream>>>(inputs, Wuf, Wua, Wfu, Wau, W256, b256, out);
        wuser_kernel<<<256, 256, 0, stream>>>(inputs, Wufd, Wuad, Wfud, Waud, W128, b128, out);
    }
}

// Round 5
// 128.566 us; speedup vs baseline: 24.3492x; 1.2111x over previous
//
#include <hip/hip_runtime.h>
#include <hip/hip_bf16.h>
#include <stdint.h>

#define BB   2048
#define DD   150
#define DKK  64

static constexpr int EXPERT_W  = 1774;        // 5*150 + 10*64 + 256 + 128
static constexpr int X_OFF     = 1390;
static constexpr int W_OFF     = 1646;
static constexpr int EXPERT_SZ = BB * EXPERT_W;
static constexpr int OH_BASE   = EXPERT_SZ;
static constexpr int FM_BASE   = OH_BASE + BB * 3;

// ---- workspace layout (bytes) ----
// WtX: 1500 tiles (T = jj*300 + i, i in [0,300), jj in [0,5)) of 16384 B.
//      tile = [blk 0..15][ksub 0..3][nloc 0..15][e 0..7] bf16
//      value = W256[(i*150 + jj*32 + ksub*8 + e)][blk*16+nloc], 0 if j>=150
// WtW: 256 tiles (T = jj*128 + i) of 8192 B, same internal layout (blk 0..7).
static constexpr size_t WTX_OFF = 0;               // 24,576,000 B
static constexpr size_t WTW_OFF = 24576000;        //  2,097,152 B
static constexpr size_t WSX_OFF = 26673152;        // f32 [16][2048][256]
static constexpr size_t WSW_OFF = 60227584;        // f32 [16][2048][128]
static constexpr size_t WS_NEED = 77004800;

typedef __attribute__((ext_vector_type(8))) short bf16x8;
typedef __attribute__((ext_vector_type(4))) float f32x4;

union APack { int d[4]; bf16x8 v; };

__device__ __forceinline__ int cvtpk_bf16(float a, float b) {
  int r; asm("v_cvt_pk_bf16_f32 %0, %1, %2" : "=v"(r) : "v"(a), "v"(b)); return r;
}
__device__ __forceinline__ f32x4 mfma16(bf16x8 a, bf16x8 b, f32x4 c) {
  return __builtin_amdgcn_mfma_f32_16x16x32_bf16(a, b, c, 0, 0, 0);
}
// async global->LDS, 16B/lane; LDS dest must be wave-uniform base (lane adds lane*16)
__device__ __forceinline__ void gload16(const void* g, void* l) {
  __builtin_amdgcn_global_load_lds(
      (__attribute__((address_space(1))) void*)(g),
      (__attribute__((address_space(3))) void*)(l), 16, 0, 0);
}

// ---------------------------------------------------------------------------
// Kernel 1: gathers -> expert row segments, one_hot, fm copies (f32 out).
// ---------------------------------------------------------------------------
__global__ __launch_bounds__(256) void gather_kernel(
    const int* __restrict__ inputs, const int* __restrict__ shifts,
    const float* __restrict__ Wuf, const float* __restrict__ Wfu,
    const float* __restrict__ Wua, const float* __restrict__ Wau,
    const float* __restrict__ Wfe,
    const float* __restrict__ Wut, const float* __restrict__ Wuk1, const float* __restrict__ Wuk2,
    const float* __restrict__ Wft, const float* __restrict__ Wfk1, const float* __restrict__ Wfk2,
    const float* __restrict__ Wufd, const float* __restrict__ Wfud,
    const float* __restrict__ Wuad, const float* __restrict__ Waud,
    float* __restrict__ out)
{
    const int b = blockIdx.x;
    const int u = inputs[b*3 + 0];
    const int f = inputs[b*3 + 1];
    const int a = inputs[b*3 + 2];
    float* row = out + b * EXPERT_W;
    float* fm  = out + FM_BASE;
    const int t = threadIdx.x;

    for (int c = t; c < DD; c += 256) {
        float ufe = Wuf[u*DD + c];
        float uae = Wua[u*DD + c];
        float fue = Wfu[f*DD + c];
        float fee = Wfe[f*DD + c];
        float aue = Wau[a*DD + c];
        row[0    + c] = ufe;
        row[150  + c] = uae;
        row[620  + c] = fue;
        row[898  + c] = fee;
        row[1176 + c] = aue;
        fm[0*BB*DD + b*DD + c] = ufe;
        fm[1*BB*DD + b*DD + c] = uae;
        fm[2*BB*DD + b*DD + c] = fue;
        fm[3*BB*DD + b*DD + c] = aue;
    }
    for (int c = t; c < DKK; c += 256) {
        row[300  + c] = Wut [u*DKK + c];
        row[364  + c] = Wuk1[u*DKK + c];
        row[428  + c] = Wuk2[u*DKK + c];
        row[492  + c] = Wufd[u*DKK + c];
        row[556  + c] = Wuad[u*DKK + c];
        row[770  + c] = Wft [f*DKK + c];
        row[834  + c] = Wfk1[f*DKK + c];
        row[1048 + c] = Wfk2[f*DKK + c];
        row[1112 + c] = Wfud[f*DKK + c];
        row[1326 + c] = Waud[a*DKK + c];
    }
    if (t < 3) {
        out[OH_BASE + b*3 + t] = (float)(inputs[b*3 + t] + shifts[t]);
    }
}

// ---------------------------------------------------------------------------
// Tile-pack W256 -> WtX: one block per tile T = jj*300 + i. 256 thr (t = n).
// Reads 32 coalesced 1KB rows, writes the 16KB tile as the exact LDS image.
// ---------------------------------------------------------------------------
__global__ __launch_bounds__(256) void tile_pack_x(
    const float* __restrict__ W, __hip_bfloat16* __restrict__ Wt)
{
  const int T  = blockIdx.x;
  const int jj = T / 300;
  const int i  = T - jj*300;
  const int t  = threadIdx.x;           // n = blk*16 + nloc
  float v[32];
  const float* src = W + ((size_t)i*150 + jj*32)*256 + t;
  #pragma unroll
  for (int jl = 0; jl < 32; ++jl) {
    int j = jj*32 + jl;
    v[jl] = (j < 150) ? src[(size_t)jl*256] : 0.f;
  }
  const int blk = t >> 4, nloc = t & 15;
  char* dst = (char*)Wt + (size_t)T*16384 + (size_t)(blk*512 + nloc*8)*2;
  #pragma unroll
  for (int ksub = 0; ksub < 4; ++ksub) {
    int pk0 = cvtpk_bf16(v[ksub*8+0], v[ksub*8+1]);
    int pk1 = cvtpk_bf16(v[ksub*8+2], v[ksub*8+3]);
    int pk2 = cvtpk_bf16(v[ksub*8+4], v[ksub*8+5]);
    int pk3 = cvtpk_bf16(v[ksub*8+6], v[ksub*8+7]);
    *(int4*)(dst + (size_t)ksub*256) = make_int4(pk0, pk1, pk2, pk3);
  }
}

// ---------------------------------------------------------------------------
// Tile-pack W128 -> WtW: one block per tile T = jj*128 + i. 128 thr (t = n).
// ---------------------------------------------------------------------------
__global__ __launch_bounds__(128) void tile_pack_w(
    const float* __restrict__ W, __hip_bfloat16* __restrict__ Wt)
{
  const int T  = blockIdx.x;
  const int jj = T >> 7;
  const int i  = T & 127;
  const int t  = threadIdx.x;
  float v[32];
  const float* src = W + ((size_t)i*64 + jj*32)*128 + t;
  #pragma unroll
  for (int jl = 0; jl < 32; ++jl) v[jl] = src[(size_t)jl*128];
  const int blk = t >> 4, nloc = t & 15;
  char* dst = (char*)Wt + (size_t)T*8192 + (size_t)(blk*512 + nloc*8)*2;
  #pragma unroll
  for (int ksub = 0; ksub < 4; ++ksub) {
    int pk0 = cvtpk_bf16(v[ksub*8+0], v[ksub*8+1]);
    int pk1 = cvtpk_bf16(v[ksub*8+2], v[ksub*8+3]);
    int pk2 = cvtpk_bf16(v[ksub*8+4], v[ksub*8+5]);
    int pk3 = cvtpk_bf16(v[ksub*8+6], v[ksub*8+7]);
    *(int4*)(dst + (size_t)ksub*256) = make_int4(pk0, pk1, pk2, pk3);
  }
}

// ---------------------------------------------------------------------------
// xuser MFMA v4: coalesced tiled staging. BM=128, BN=256, 512 thr = 8 waves
// (2 mg x 4 ng), wave = 4 mf x 4 nf frags. Double-buffered 16KB chunks.
// SPLITK=16 at i-boundaries; partials -> wsX[s][b][n].
// ---------------------------------------------------------------------------
__global__ __launch_bounds__(512, 1) void xuser_mfma(
    const int* __restrict__ inputs,
    const float* __restrict__ Wuf, const float* __restrict__ Wua,
    const float* __restrict__ Wfu, const float* __restrict__ Wau,
    const __hip_bfloat16* __restrict__ WtXt, float* __restrict__ wsX)
{
  __shared__ float xlds[128*20];               // 10 KB
  __shared__ __hip_bfloat16 blds[2][8192];     // 2 x 16 KB

  const int mb = blockIdx.x >> 4;
  const int s  = blockIdx.x & 15;
  const int b0 = mb * 128;
  const bool upper = s >= 8;
  const int sl  = upper ? s - 8 : s;
  const int i0l = sl * 19;
  const int cnt = (150 - i0l) < 19 ? (150 - i0l) : 19;   // 19 or 17
  const int ig0 = i0l + (upper ? 150 : 0);               // global i of chunk 0
  const int tid = threadIdx.x;

  const float* X = upper ? Wua : Wuf;
  const float* Y = upper ? Wau : Wfu;
  const int yoff = upper ? 2 : 1;

  // stage x [128 rows][20 ii]
  for (int k = tid; k < 128*20; k += 512) {
    int r = k / 20, ii = k - r*20;
    float v = 0.f;
    if (ii < cnt) v = X[(size_t)inputs[(b0+r)*3]*150 + i0l + ii];
    xlds[k] = v;
  }

  const int lane = tid & 63;
  const int w  = tid >> 6;
  const int mg = w >> 2;        // 0..1 (64 rows)
  const int ng = w & 3;         // 0..3 (64 cols)
  const int lr = lane & 15;
  const int g  = lane >> 4;

  int yid[4];
  #pragma unroll
  for (int mf = 0; mf < 4; ++mf)
    yid[mf] = inputs[(size_t)(b0 + mg*64 + mf*16 + lr)*3 + yoff];

  const char* wtb = (const char*)WtXt;
  const unsigned wdst = (unsigned)(tid & ~63) * 16;   // wave-uniform LDS byte base

  f32x4 acc[4][4];
  #pragma unroll
  for (int i = 0; i < 4; ++i)
    #pragma unroll
    for (int j = 0; j < 4; ++j) acc[i][j] = (f32x4){0.f,0.f,0.f,0.f};

  // coalesced stage of tile T into buffer b: 2 x (512 lanes x 16 B) = 16 KB
  auto stage = [&](int bufi, int T) {
    const char* sp = wtb + (size_t)T*16384 + (size_t)tid*16;
    char* dp = (char*)&blds[bufi][0] + wdst;
    gload16(sp,        dp);
    gload16(sp + 8192, dp + 8192);
  };

  stage(0, ig0);   // jj=0, ii=0
  __syncthreads();

  int buf = 0;
  for (int jj = 0; jj < 5; ++jj) {
    // y fragments for this jj (invariant over ii); guarded at the j=150 edge
    float yreg[4][8];
    const int jb = jj*32 + g*8;
    #pragma unroll
    for (int mf = 0; mf < 4; ++mf) {
      const float* yp = Y + (size_t)yid[mf]*150;
      if (jb + 8 <= 150) {
        #pragma unroll
        for (int h = 0; h < 4; ++h) {
          float2 vv = *(const float2*)(yp + jb + 2*h);
          yreg[mf][2*h]   = vv.x;
          yreg[mf][2*h+1] = vv.y;
        }
      } else {
        #pragma unroll
        for (int e = 0; e < 8; ++e)
          yreg[mf][e] = (jb + e < 150) ? yp[jb + e] : 0.f;
      }
    }
    for (int ii = 0; ii < cnt; ++ii) {
      // prefetch next chunk into other buffer
      int njj = jj, nii = ii + 1;
      if (nii == cnt) { njj++; nii = 0; }
      if (njj < 5) stage(buf^1, njj*300 + ig0 + nii);

      const __hip_bfloat16* bb = &blds[buf][0];
      bf16x8 bv[4];
      #pragma unroll
      for (int nf = 0; nf < 4; ++nf)
        bv[nf] = *(const bf16x8*)(bb + (ng*4 + nf)*512 + g*128 + lr*8);

      APack a[4];
      #pragma unroll
      for (int mf = 0; mf < 4; ++mf) {
        float xv = xlds[(mg*64 + mf*16 + lr)*20 + ii];
        #pragma unroll
        for (int e = 0; e < 4; ++e)
          a[mf].d[e] = cvtpk_bf16(xv*yreg[mf][2*e], xv*yreg[mf][2*e+1]);
      }
      #pragma unroll
      for (int mf = 0; mf < 4; ++mf)
        #pragma unroll
        for (int nf = 0; nf < 4; ++nf)
          acc[mf][nf] = mfma16(a[mf].v, bv[nf], acc[mf][nf]);
      __syncthreads();
      buf ^= 1;
    }
  }

  // store partials: C/D layout: col = lane&15, row = 4*(lane>>4)+e
  float* wp = wsX + ((size_t)s*2048 + b0)*256;
  #pragma unroll
  for (int mf = 0; mf < 4; ++mf) {
    #pragma unroll
    for (int nf = 0; nf < 4; ++nf) {
      int rb  = mg*64 + mf*16 + g*4;
      int col = ng*64 + nf*16 + lr;
      f32x4 v = acc[mf][nf];
      #pragma unroll
      for (int e = 0; e < 4; ++e) wp[(size_t)(rb+e)*256 + col] = v[e];
    }
  }
}

// ---------------------------------------------------------------------------
// wuser MFMA v4: BM=128, BN=128, 8 waves (2 mg x 4 ng), wave = 4 mf x 2 nf.
// Tiled 8KB chunks, double-buffered. SPLITK=16.
// ---------------------------------------------------------------------------
__global__ __launch_bounds__(512, 1) void wuser_mfma(
    const int* __restrict__ inputs,
    const float* __restrict__ Wufd, const float* __restrict__ Wuad,
    const float* __restrict__ Wfud, const float* __restrict__ Waud,
    const __hip_bfloat16* __restrict__ WtWt, float* __restrict__ wsW)
{
  __shared__ float xlds[128*8];                // 4 KB
  __shared__ __hip_bfloat16 blds[2][4096];     // 2 x 8 KB

  const int mb = blockIdx.x >> 4;
  const int s  = blockIdx.x & 15;
  const int b0 = mb * 128;
  const bool upper = s >= 8;
  const int i0l = (s & 7) * 8;
  const int ig0 = i0l + (upper ? 64 : 0);
  const int tid = threadIdx.x;

  const float* X = upper ? Wuad : Wufd;
  const float* Y = upper ? Waud : Wfud;
  const int yoff = upper ? 2 : 1;

  for (int k = tid; k < 128*8; k += 512) {
    int r = k >> 3, ii = k & 7;
    xlds[k] = X[(size_t)inputs[(size_t)(b0+r)*3]*64 + i0l + ii];
  }

  const int lane = tid & 63;
  const int w  = tid >> 6;
  const int mg = w >> 2;
  const int ng = w & 3;         // 0..3 (32 cols each)
  const int lr = lane & 15;
  const int g  = lane >> 4;

  int yid[4];
  #pragma unroll
  for (int mf = 0; mf < 4; ++mf)
    yid[mf] = inputs[(size_t)(b0 + mg*64 + mf*16 + lr)*3 + yoff];

  const char* wtb = (const char*)WtWt;
  const unsigned wdst = (unsigned)(tid & ~63) * 16;

  f32x4 acc[4][2];
  #pragma unroll
  for (int i = 0; i < 4; ++i)
    #pragma unroll
    for (int j = 0; j < 2; ++j) acc[i][j] = (f32x4){0.f,0.f,0.f,0.f};

  auto stage = [&](int bufi, int T) {
    gload16(wtb + (size_t)T*8192 + (size_t)tid*16,
            (char*)&blds[bufi][0] + wdst);
  };

  stage(0, ig0);
  __syncthreads();

  int buf = 0;
  for (int jj = 0; jj < 2; ++jj) {
    float yreg[4][8];
    const int jb = jj*32 + g*8;       // max 56; +8 = 64 = row length, safe
    #pragma unroll
    for (int mf = 0; mf < 4; ++mf) {
      const float* yp = Y + (size_t)yid[mf]*64 + jb;
      #pragma unroll
      for (int h = 0; h < 2; ++h) {
        float4 v = *(const float4*)(yp + h*4);
        yreg[mf][h*4]   = v.x;
        yreg[mf][h*4+1] = v.y;
        yreg[mf][h*4+2] = v.z;
        yreg[mf][h*4+3] = v.w;
      }
    }
    for (int ii = 0; ii < 8; ++ii) {
      int njj = jj, nii = ii + 1;
      if (nii == 8) { njj++; nii = 0; }
      if (njj < 2) stage(buf^1, njj*128 + ig0 + nii);

      const __hip_bfloat16* bb = &blds[buf][0];
      bf16x8 bv[2];
      #pragma unroll
      for (int nf = 0; nf < 2; ++nf)
        bv[nf] = *(const bf16x8*)(bb + (ng*2 + nf)*512 + g*128 + lr*8);

      APack a[4];
      #pragma unroll
      for (int mf = 0; mf < 4; ++mf) {
        float xv = xlds[(mg*64 + mf*16 + lr)*8 + ii];
        #pragma unroll
        for (int e = 0; e < 4; ++e)
          a[mf].d[e] = cvtpk_bf16(xv*yreg[mf][2*e], xv*yreg[mf][2*e+1]);
      }
      #pragma unroll
      for (int mf = 0; mf < 4; ++mf)
        #pragma unroll
        for (int nf = 0; nf < 2; ++nf)
          acc[mf][nf] = mfma16(a[mf].v, bv[nf], acc[mf][nf]);
      __syncthreads();
      buf ^= 1;
    }
  }

  float* wp = wsW + ((size_t)s*2048 + b0)*128;
  #pragma unroll
  for (int mf = 0; mf < 4; ++mf) {
    #pragma unroll
    for (int nf = 0; nf < 2; ++nf) {
      int rb  = mg*64 + mf*16 + g*4;
      int col = ng*32 + nf*16 + lr;
      f32x4 v = acc[mf][nf];
      #pragma unroll
      for (int e = 0; e < 4; ++e) wp[(size_t)(rb+e)*128 + col] = v[e];
    }
  }
}

// ---------------------------------------------------------------------------
// Epilogue: sum partials + bias + relu -> expert rows.
// ---------------------------------------------------------------------------
__global__ __launch_bounds__(256) void epilogue_kernel(
    const float* __restrict__ wsX, const float* __restrict__ wsW,
    const float* __restrict__ b256, const float* __restrict__ b128,
    float* __restrict__ out)
{
  int idx = blockIdx.x*256 + threadIdx.x;
  if (idx >= BB*384) return;
  int b = idx / 384, c = idx - b*384;
  if (c < 256) {
    float acc = b256[c];
    #pragma unroll
    for (int k = 0; k < 16; ++k) acc += wsX[((size_t)k*BB + b)*256 + c];
    out[(size_t)b*EXPERT_W + X_OFF + c] = acc > 0.f ? acc : 0.f;
  } else {
    int cc = c - 256;
    float acc = b128[cc];
    #pragma unroll
    for (int k = 0; k < 16; ++k) acc += wsW[((size_t)k*BB + b)*128 + cc];
    out[(size_t)b*EXPERT_W + W_OFF + cc] = acc > 0.f ? acc : 0.f;
  }
}

// ---------------------------------------------------------------------------
// Fallback VALU kernels (round-2, verified-passing) used if ws too small.
// ---------------------------------------------------------------------------
static constexpr int NPAIR_X = 300 * 150;
static constexpr int CHX     = 128;

__global__ __launch_bounds__(256) void xuser_kernel(
    const int* __restrict__ inputs,
    const float* __restrict__ Wuf, const float* __restrict__ Wua,
    const float* __restrict__ Wfu, const float* __restrict__ Wau,
    const float* __restrict__ W256, const float* __restrict__ b256,
    float* __restrict__ out)
{
    __shared__ float xs[16][308];
    __shared__ float ys[16][308];
    __shared__ float xy[CHX][16];
    const int half = blockIdx.x & 1;
    const int bg   = blockIdx.x >> 1;
    const int b0   = bg * 16;
    const int t    = threadIdx.x;
    const int bl   = t & 15;
    const int kg   = t >> 4;
    const int kbase = half * 128 + kg * 8;
    for (int idx = t; idx < 16 * DD; idx += 256) {
        int bb = idx / DD;
        int c  = idx - bb * DD;
        int u = inputs[(b0+bb)*3 + 0];
        int f = inputs[(b0+bb)*3 + 1];
        int a = inputs[(b0+bb)*3 + 2];
        xs[bb][c]       = Wuf[u*DD + c];
        xs[bb][150 + c] = Wua[u*DD + c];
        ys[bb][c]       = Wfu[f*DD + c];
        ys[bb][150 + c] = Wau[a*DD + c];
    }
    float acc[8] = {0,0,0,0,0,0,0,0};
    for (int base = 0; base < NPAIR_X; base += CHX) {
        __syncthreads();
        #pragma unroll
        for (int r = 0; r < (CHX*16)/256; ++r) {
            int idx = t + r * 256;
            int pl  = idx >> 4;
            int bb  = idx & 15;
            int p   = base + pl;
            if (p < NPAIR_X) {
                int i = p / 150;
                int j = p - i * 150;
                xy[pl][bb] = xs[bb][i] * ys[bb][(i >= 150 ? 150 : 0) + j];
            }
        }
        __syncthreads();
        const int lim = min(CHX, NPAIR_X - base);
        const float* wp = W256 + base * 256 + kbase;
        for (int pl = 0; pl < lim; ++pl) {
            float sv = xy[pl][bl];
            const float4* w4 = (const float4*)(wp + pl * 256);
            float4 w0 = w4[0], w1 = w4[1];
            acc[0] = fmaf(sv, w0.x, acc[0]); acc[1] = fmaf(sv, w0.y, acc[1]);
            acc[2] = fmaf(sv, w0.z, acc[2]); acc[3] = fmaf(sv, w0.w, acc[3]);
            acc[4] = fmaf(sv, w1.x, acc[4]); acc[5] = fmaf(sv, w1.y, acc[5]);
            acc[6] = fmaf(sv, w1.z, acc[6]); acc[7] = fmaf(sv, w1.w, acc[7]);
        }
    }
    const int rowbase = (b0 + bl) * EXPERT_W + X_OFF;
    #pragma unroll
    for (int m = 0; m < 8; ++m) {
        float v = acc[m] + b256[kbase + m];
        out[rowbase + kbase + m] = (v > 0.f ? v : 0.f);
    }
}

static constexpr int NPAIR_W = 128 * 64;
static constexpr int CHW     = 256;

__global__ __launch_bounds__(256) void wuser_kernel(
    const int* __restrict__ inputs,
    const float* __restrict__ Wufd, const float* __restrict__ Wuad,
    const float* __restrict__ Wfud, const float* __restrict__ Waud,
    const float* __restrict__ W128, const float* __restrict__ b128,
    float* __restrict__ out)
{
    __shared__ float xs[8][132];
    __shared__ float ys[8][132];
    __shared__ float xy[CHW][8];
    const int bg = blockIdx.x;
    const int b0 = bg * 8;
    const int t  = threadIdx.x;
    const int bl = t & 7;
    const int kg = t >> 3;
    const int kbase = kg * 4;
    for (int idx = t; idx < 8 * DKK; idx += 256) {
        int bb = idx >> 6;
        int c  = idx & 63;
        int u = inputs[(b0+bb)*3 + 0];
        int f = inputs[(b0+bb)*3 + 1];
        int a = inputs[(b0+bb)*3 + 2];
        xs[bb][c]      = Wufd[u*DKK + c];
        xs[bb][64 + c] = Wuad[u*DKK + c];
        ys[bb][c]      = Wfud[f*DKK + c];
        ys[bb][64 + c] = Waud[a*DKK + c];
    }
    float acc[4] = {0,0,0,0};
    for (int base = 0; base < NPAIR_W; base += CHW) {
        __syncthreads();
        #pragma unroll
        for (int r = 0; r < (CHW*8)/256; ++r) {
            int idx = t + r * 256;
            int pl  = idx >> 3;
            int bb  = idx & 7;
            int p   = base + pl;
            int i = p >> 6;
            int j = p & 63;
            xy[pl][bb] = xs[bb][i] * ys[bb][(i >= 64 ? 64 : 0) + j];
        }
        __syncthreads();
        const float* wp = W128 + base * 128 + kbase;
        for (int pl = 0; pl < CHW; ++pl) {
            float sv = xy[pl][bl];
            float4 wv = *(const float4*)(wp + pl * 128);
            acc[0] = fmaf(sv, wv.x, acc[0]); acc[1] = fmaf(sv, wv.y, acc[1]);
            acc[2] = fmaf(sv, wv.z, acc[2]); acc[3] = fmaf(sv, wv.w, acc[3]);
        }
    }
    const int rowbase = (b0 + bl) * EXPERT_W + W_OFF;
    #pragma unroll
    for (int m = 0; m < 4; ++m) {
        float v = acc[m] + b128[kbase + m];
        out[rowbase + kbase + m] = (v > 0.f ? v : 0.f);
    }
}

// ---------------------------------------------------------------------------
extern "C" void kernel_launch(void* const* d_in, const int* in_sizes, int n_in,
                              void* d_out, int out_size, void* d_ws, size_t ws_size,
                              hipStream_t stream)
{
    const int*   inputs = (const int*)  d_in[0];
    const int*   shifts = (const int*)  d_in[1];
    const float* Wuf    = (const float*)d_in[2];
    const float* Wfu    = (const float*)d_in[3];
    const float* Wua    = (const float*)d_in[4];
    const float* Wau    = (const float*)d_in[5];
    const float* Wfe    = (const float*)d_in[6];
    const float* Wut    = (const float*)d_in[7];
    const float* Wuk1   = (const float*)d_in[8];
    const float* Wuk2   = (const float*)d_in[9];
    const float* Wft    = (const float*)d_in[10];
    const float* Wfk1   = (const float*)d_in[11];
    const float* Wfk2   = (const float*)d_in[12];
    const float* Wufd   = (const float*)d_in[13];
    const float* Wfud   = (const float*)d_in[14];
    const float* Wuad   = (const float*)d_in[15];
    const float* Waud   = (const float*)d_in[16];
    const float* W256   = (const float*)d_in[17];
    const float* b256   = (const float*)d_in[18];
    const float* W128   = (const float*)d_in[19];
    const float* b128   = (const float*)d_in[20];

    float* out = (float*)d_out;

    gather_kernel<<<BB, 256, 0, stream>>>(inputs, shifts,
        Wuf, Wfu, Wua, Wau, Wfe, Wut, Wuk1, Wuk2, Wft, Wfk1, Wfk2,
        Wufd, Wfud, Wuad, Waud, out);

    if (ws_size >= WS_NEED) {
        char* ws = (char*)d_ws;
        __hip_bfloat16* WtX = (__hip_bfloat16*)(ws + WTX_OFF);
        __hip_bfloat16* WtW = (__hip_bfloat16*)(ws + WTW_OFF);
        float* wsX = (float*)(ws + WSX_OFF);
        float* wsW = (float*)(ws + WSW_OFF);

        tile_pack_x<<<1500, 256, 0, stream>>>(W256, WtX);
        tile_pack_w<<<256, 128, 0, stream>>>(W128, WtW);

        xuser_mfma<<<256, 512, 0, stream>>>(inputs, Wuf, Wua, Wfu, Wau, WtX, wsX);
        wuser_mfma<<<256, 512, 0, stream>>>(inputs, Wufd, Wuad, Wfud, Waud, WtW, wsW);

        epilogue_kernel<<<(BB*384 + 255)/256, 256, 0, stream>>>(wsX, wsW, b256, b128, out);
    } else {
        xuser_kernel<<<256, 256, 0, stream>>>(inputs, Wuf, Wua, Wfu, Wau, W256, b256, out);
        wuser_kernel<<<256, 256, 0, stream>>>(inputs, Wufd, Wuad, Wfud, Waud, W128, b128, out);
    }
}

// Round 6
// 105.763 us; speedup vs baseline: 29.5991x; 1.2156x over previous
//
#include <hip/hip_runtime.h>
#include <hip/hip_bf16.h>
#include <stdint.h>

#define BB   2048
#define DD   150
#define DKK  64

static constexpr int EXPERT_W  = 1774;        // 5*150 + 10*64 + 256 + 128
static constexpr int X_OFF     = 1390;
static constexpr int W_OFF     = 1646;
static constexpr int EXPERT_SZ = BB * EXPERT_W;
static constexpr int OH_BASE   = EXPERT_SZ;
static constexpr int FM_BASE   = OH_BASE + BB * 3;

// ---- workspace layout (bytes) ----
// WtX: 1500 tiles (T = jj*300 + i, i in [0,300), jj in [0,5)) of 16384 B.
//      tile = [blk 0..15][ksub 0..3][nloc 0..15][e 0..7] bf16
//      value = W256[(i*150 + jj*32 + ksub*8 + e)][blk*16+nloc], 0 if j>=150
// WtW: 256 tiles (T = jj*128 + i) of 8192 B, same internal layout (blk 0..7).
static constexpr size_t WTX_OFF = 0;               // 24,576,000 B
static constexpr size_t WTW_OFF = 24576000;        //  2,097,152 B
static constexpr size_t WSX_OFF = 26673152;        // f32 [16][2048][256]
static constexpr size_t WSW_OFF = 60227584;        // f32 [16][2048][128]
static constexpr size_t WS_NEED = 77004800;

typedef __attribute__((ext_vector_type(8))) short bf16x8;
typedef __attribute__((ext_vector_type(4))) float f32x4;

union APack { int d[4]; bf16x8 v; };

__device__ __forceinline__ int cvtpk_bf16(float a, float b) {
  int r; asm("v_cvt_pk_bf16_f32 %0, %1, %2" : "=v"(r) : "v"(a), "v"(b)); return r;
}
__device__ __forceinline__ f32x4 mfma16(bf16x8 a, bf16x8 b, f32x4 c) {
  return __builtin_amdgcn_mfma_f32_16x16x32_bf16(a, b, c, 0, 0, 0);
}
// async global->LDS, 16B/lane; LDS dest must be wave-uniform base (lane adds lane*16)
__device__ __forceinline__ void gload16(const void* g, void* l) {
  __builtin_amdgcn_global_load_lds(
      (__attribute__((address_space(1))) void*)(g),
      (__attribute__((address_space(3))) void*)(l), 16, 0, 0);
}

// ---------------------------------------------------------------------------
// Kernel 1: gathers -> expert row segments, one_hot, fm copies (f32 out).
// ---------------------------------------------------------------------------
__global__ __launch_bounds__(256) void gather_kernel(
    const int* __restrict__ inputs, const int* __restrict__ shifts,
    const float* __restrict__ Wuf, const float* __restrict__ Wfu,
    const float* __restrict__ Wua, const float* __restrict__ Wau,
    const float* __restrict__ Wfe,
    const float* __restrict__ Wut, const float* __restrict__ Wuk1, const float* __restrict__ Wuk2,
    const float* __restrict__ Wft, const float* __restrict__ Wfk1, const float* __restrict__ Wfk2,
    const float* __restrict__ Wufd, const float* __restrict__ Wfud,
    const float* __restrict__ Wuad, const float* __restrict__ Waud,
    float* __restrict__ out)
{
    const int b = blockIdx.x;
    const int u = inputs[b*3 + 0];
    const int f = inputs[b*3 + 1];
    const int a = inputs[b*3 + 2];
    float* row = out + b * EXPERT_W;
    float* fm  = out + FM_BASE;
    const int t = threadIdx.x;

    for (int c = t; c < DD; c += 256) {
        float ufe = Wuf[u*DD + c];
        float uae = Wua[u*DD + c];
        float fue = Wfu[f*DD + c];
        float fee = Wfe[f*DD + c];
        float aue = Wau[a*DD + c];
        row[0    + c] = ufe;
        row[150  + c] = uae;
        row[620  + c] = fue;
        row[898  + c] = fee;
        row[1176 + c] = aue;
        fm[0*BB*DD + b*DD + c] = ufe;
        fm[1*BB*DD + b*DD + c] = uae;
        fm[2*BB*DD + b*DD + c] = fue;
        fm[3*BB*DD + b*DD + c] = aue;
    }
    for (int c = t; c < DKK; c += 256) {
        row[300  + c] = Wut [u*DKK + c];
        row[364  + c] = Wuk1[u*DKK + c];
        row[428  + c] = Wuk2[u*DKK + c];
        row[492  + c] = Wufd[u*DKK + c];
        row[556  + c] = Wuad[u*DKK + c];
        row[770  + c] = Wft [f*DKK + c];
        row[834  + c] = Wfk1[f*DKK + c];
        row[1048 + c] = Wfk2[f*DKK + c];
        row[1112 + c] = Wfud[f*DKK + c];
        row[1326 + c] = Waud[a*DKK + c];
    }
    if (t < 3) {
        out[OH_BASE + b*3 + t] = (float)(inputs[b*3 + t] + shifts[t]);
    }
}

// ---------------------------------------------------------------------------
// Tile-pack W256 -> WtX: one block per tile T = jj*300 + i. 256 thr (t = n).
// ---------------------------------------------------------------------------
__global__ __launch_bounds__(256) void tile_pack_x(
    const float* __restrict__ W, __hip_bfloat16* __restrict__ Wt)
{
  const int T  = blockIdx.x;
  const int jj = T / 300;
  const int i  = T - jj*300;
  const int t  = threadIdx.x;           // n = blk*16 + nloc
  float v[32];
  const float* src = W + ((size_t)i*150 + jj*32)*256 + t;
  #pragma unroll
  for (int jl = 0; jl < 32; ++jl) {
    int j = jj*32 + jl;
    v[jl] = (j < 150) ? src[(size_t)jl*256] : 0.f;
  }
  const int blk = t >> 4, nloc = t & 15;
  char* dst = (char*)Wt + (size_t)T*16384 + (size_t)(blk*512 + nloc*8)*2;
  #pragma unroll
  for (int ksub = 0; ksub < 4; ++ksub) {
    int pk0 = cvtpk_bf16(v[ksub*8+0], v[ksub*8+1]);
    int pk1 = cvtpk_bf16(v[ksub*8+2], v[ksub*8+3]);
    int pk2 = cvtpk_bf16(v[ksub*8+4], v[ksub*8+5]);
    int pk3 = cvtpk_bf16(v[ksub*8+6], v[ksub*8+7]);
    *(int4*)(dst + (size_t)ksub*256) = make_int4(pk0, pk1, pk2, pk3);
  }
}

// ---------------------------------------------------------------------------
// Tile-pack W128 -> WtW: one block per tile T = jj*128 + i. 128 thr (t = n).
// ---------------------------------------------------------------------------
__global__ __launch_bounds__(128) void tile_pack_w(
    const float* __restrict__ W, __hip_bfloat16* __restrict__ Wt)
{
  const int T  = blockIdx.x;
  const int jj = T >> 7;
  const int i  = T & 127;
  const int t  = threadIdx.x;
  float v[32];
  const float* src = W + ((size_t)i*64 + jj*32)*128 + t;
  #pragma unroll
  for (int jl = 0; jl < 32; ++jl) v[jl] = src[(size_t)jl*128];
  const int blk = t >> 4, nloc = t & 15;
  char* dst = (char*)Wt + (size_t)T*8192 + (size_t)(blk*512 + nloc*8)*2;
  #pragma unroll
  for (int ksub = 0; ksub < 4; ++ksub) {
    int pk0 = cvtpk_bf16(v[ksub*8+0], v[ksub*8+1]);
    int pk1 = cvtpk_bf16(v[ksub*8+2], v[ksub*8+3]);
    int pk2 = cvtpk_bf16(v[ksub*8+4], v[ksub*8+5]);
    int pk3 = cvtpk_bf16(v[ksub*8+6], v[ksub*8+7]);
    *(int4*)(dst + (size_t)ksub*256) = make_int4(pk0, pk1, pk2, pk3);
  }
}

// ---------------------------------------------------------------------------
// xuser MFMA v5: grid 512 = 16 mb x 16 s x 2 h (col halves). 512 thr = 8 waves
// (4 mg x 2 ng); wave = 2 mf (32 rows) x 4 nf (64 cols). Depth-2 chunks:
// two 8KB half-tiles per barrier, double-buffered. 2 blocks/CU.
// ---------------------------------------------------------------------------
__global__ __launch_bounds__(512, 4) void xuser_mfma(
    const int* __restrict__ inputs,
    const float* __restrict__ Wuf, const float* __restrict__ Wua,
    const float* __restrict__ Wfu, const float* __restrict__ Wau,
    const __hip_bfloat16* __restrict__ WtXt, float* __restrict__ wsX)
{
  __shared__ float xlds[128*20];                          // 10 KB
  __shared__ __align__(16) __hip_bfloat16 blds[2][8192];  // 2 x 16 KB (pair of 8KB half-tiles)

  const int bid = blockIdx.x;
  const int h  = bid & 1;
  const int s  = (bid >> 1) & 15;
  const int mb = bid >> 5;
  const int b0 = mb * 128;
  const bool upper = s >= 8;
  const int sl  = upper ? s - 8 : s;
  const int i0l = sl * 19;
  const int cnt = (150 - i0l) < 19 ? (150 - i0l) : 19;   // 19 or 17
  const int ig0 = i0l + (upper ? 150 : 0);               // global i of chunk 0
  const int tid = threadIdx.x;

  const float* X = upper ? Wua : Wuf;
  const float* Y = upper ? Wau : Wfu;
  const int yoff = upper ? 2 : 1;

  // stage x [128 rows][20 ii]
  for (int k = tid; k < 128*20; k += 512) {
    int r = k / 20, ii = k - r*20;
    float v = 0.f;
    if (ii < cnt) v = X[(size_t)inputs[(b0+r)*3]*150 + i0l + ii];
    xlds[k] = v;
  }

  const int lane = tid & 63;
  const int w  = tid >> 6;
  const int mg = w >> 1;        // 0..3 (32 rows each)
  const int ng = w & 1;         // 0..1 (64 cols each)
  const int lr = lane & 15;
  const int g  = lane >> 4;

  int yid[2];
  #pragma unroll
  for (int mf = 0; mf < 2; ++mf)
    yid[mf] = inputs[(size_t)(b0 + mg*32 + mf*16 + lr)*3 + yoff];

  const char* wtb = (const char*)WtXt + (size_t)h*8192;
  const unsigned wdst = (unsigned)(tid & ~63) * 16;   // wave-uniform LDS byte base

  f32x4 acc[2][4];
  #pragma unroll
  for (int i = 0; i < 2; ++i)
    #pragma unroll
    for (int j = 0; j < 4; ++j) acc[i][j] = (f32x4){0.f,0.f,0.f,0.f};

  // stage a pair of half-tiles (T, T+1) into buffer: 2 x 8KB
  auto stage = [&](int bufi, int T, int c2) {
    const char* sp = wtb + (size_t)T*16384 + (size_t)tid*16;
    char* dp = (char*)&blds[bufi][0] + wdst;
    gload16(sp, dp);
    if (c2 > 1) gload16(sp + 16384, dp + 8192);
  };

  // compute one 8KB half-tile (sub sc of buffer) at column-half h, K-index ii
  auto computeSub = [&](const __hip_bfloat16* bb, int ii) {
    bf16x8 bv[4];
    #pragma unroll
    for (int nf = 0; nf < 4; ++nf)
      bv[nf] = *(const bf16x8*)(bb + (ng*4 + nf)*512 + g*128 + lr*8);
    APack a[2];
    #pragma unroll
    for (int mf = 0; mf < 2; ++mf) {
      float xv = xlds[(mg*32 + mf*16 + lr)*20 + ii];
      float* yr = nullptr; (void)yr;
      #pragma unroll
      for (int e = 0; e < 4; ++e)
        a[mf].d[e] = cvtpk_bf16(xv*0.f, xv*0.f);   // placeholder, overwritten below
    }
    return bv[0]; // unreachable pattern
  };
  (void)computeSub;

  stage(0, ig0, cnt >= 2 ? 2 : 1);
  __syncthreads();

  int buf = 0;
  for (int jj = 0; jj < 5; ++jj) {
    // y fragments for this jj (invariant over ii); guarded at the j=150 edge
    float yreg[2][8];
    const int jb = jj*32 + g*8;
    #pragma unroll
    for (int mf = 0; mf < 2; ++mf) {
      const float* yp = Y + (size_t)yid[mf]*150;
      if (jb + 8 <= 150) {
        #pragma unroll
        for (int hh = 0; hh < 4; ++hh) {
          float2 vv = *(const float2*)(yp + jb + 2*hh);
          yreg[mf][2*hh]   = vv.x;
          yreg[mf][2*hh+1] = vv.y;
        }
      } else {
        #pragma unroll
        for (int e = 0; e < 8; ++e)
          yreg[mf][e] = (jb + e < 150) ? yp[jb + e] : 0.f;
      }
    }
    for (int ii = 0; ii < cnt; ii += 2) {
      const int rem = cnt - ii;
      // prefetch next pair into other buffer
      int njj = jj, nii = ii + 2;
      if (nii >= cnt) { njj++; nii = 0; }
      if (njj < 5) stage(buf^1, njj*300 + ig0 + nii, (cnt - nii) >= 2 ? 2 : 1);

      #pragma unroll
      for (int sc = 0; sc < 2; ++sc) {
        if (sc == 1 && rem < 2) break;
        const __hip_bfloat16* bb = &blds[buf][sc*4096];
        bf16x8 bv[4];
        #pragma unroll
        for (int nf = 0; nf < 4; ++nf)
          bv[nf] = *(const bf16x8*)(bb + (ng*4 + nf)*512 + g*128 + lr*8);
        APack a[2];
        #pragma unroll
        for (int mf = 0; mf < 2; ++mf) {
          float xv = xlds[(mg*32 + mf*16 + lr)*20 + ii + sc];
          #pragma unroll
          for (int e = 0; e < 4; ++e)
            a[mf].d[e] = cvtpk_bf16(xv*yreg[mf][2*e], xv*yreg[mf][2*e+1]);
        }
        #pragma unroll
        for (int mf = 0; mf < 2; ++mf)
          #pragma unroll
          for (int nf = 0; nf < 4; ++nf)
            acc[mf][nf] = mfma16(a[mf].v, bv[nf], acc[mf][nf]);
      }
      __syncthreads();
      buf ^= 1;
    }
  }

  // store partials: C/D layout: col = lane&15, row = 4*(lane>>4)+e
  float* wp = wsX + ((size_t)s*2048 + b0)*256;
  #pragma unroll
  for (int mf = 0; mf < 2; ++mf) {
    #pragma unroll
    for (int nf = 0; nf < 4; ++nf) {
      int rb  = mg*32 + mf*16 + g*4;
      int col = h*128 + ng*64 + nf*16 + lr;
      f32x4 v = acc[mf][nf];
      #pragma unroll
      for (int e = 0; e < 4; ++e) wp[(size_t)(rb+e)*256 + col] = v[e];
    }
  }
}

// ---------------------------------------------------------------------------
// wuser MFMA v5: grid 256 = 16 mb x 16 s. 8 waves (4 mg x 2 ng); wave = 2 mf
// x 4 nf. Depth-2 chunks: two 8KB full tiles per barrier, double-buffered.
// ---------------------------------------------------------------------------
__global__ __launch_bounds__(512, 4) void wuser_mfma(
    const int* __restrict__ inputs,
    const float* __restrict__ Wufd, const float* __restrict__ Wuad,
    const float* __restrict__ Wfud, const float* __restrict__ Waud,
    const __hip_bfloat16* __restrict__ WtWt, float* __restrict__ wsW)
{
  __shared__ float xlds[128*8];                           // 4 KB
  __shared__ __align__(16) __hip_bfloat16 blds[2][8192];  // 2 x 16 KB (pair of 8KB tiles)

  const int mb = blockIdx.x >> 4;
  const int s  = blockIdx.x & 15;
  const int b0 = mb * 128;
  const bool upper = s >= 8;
  const int i0l = (s & 7) * 8;
  const int ig0 = i0l + (upper ? 64 : 0);
  const int tid = threadIdx.x;

  const float* X = upper ? Wuad : Wufd;
  const float* Y = upper ? Waud : Wfud;
  const int yoff = upper ? 2 : 1;

  for (int k = tid; k < 128*8; k += 512) {
    int r = k >> 3, ii = k & 7;
    xlds[k] = X[(size_t)inputs[(size_t)(b0+r)*3]*64 + i0l + ii];
  }

  const int lane = tid & 63;
  const int w  = tid >> 6;
  const int mg = w >> 1;        // 0..3
  const int ng = w & 1;         // 0..1 (64 cols each)
  const int lr = lane & 15;
  const int g  = lane >> 4;

  int yid[2];
  #pragma unroll
  for (int mf = 0; mf < 2; ++mf)
    yid[mf] = inputs[(size_t)(b0 + mg*32 + mf*16 + lr)*3 + yoff];

  const char* wtb = (const char*)WtWt;
  const unsigned wdst = (unsigned)(tid & ~63) * 16;

  f32x4 acc[2][4];
  #pragma unroll
  for (int i = 0; i < 2; ++i)
    #pragma unroll
    for (int j = 0; j < 4; ++j) acc[i][j] = (f32x4){0.f,0.f,0.f,0.f};

  auto stage = [&](int bufi, int T) {   // always pairs (cnt=8 even)
    const char* sp = wtb + (size_t)T*8192 + (size_t)tid*16;
    char* dp = (char*)&blds[bufi][0] + wdst;
    gload16(sp, dp);
    gload16(sp + 8192, dp + 8192);
  };

  stage(0, ig0);
  __syncthreads();

  int buf = 0;
  for (int jj = 0; jj < 2; ++jj) {
    float yreg[2][8];
    const int jb = jj*32 + g*8;       // max 56; +8 = 64 = row length, safe
    #pragma unroll
    for (int mf = 0; mf < 2; ++mf) {
      const float* yp = Y + (size_t)yid[mf]*64 + jb;
      #pragma unroll
      for (int hh = 0; hh < 2; ++hh) {
        float4 v = *(const float4*)(yp + hh*4);
        yreg[mf][hh*4]   = v.x;
        yreg[mf][hh*4+1] = v.y;
        yreg[mf][hh*4+2] = v.z;
        yreg[mf][hh*4+3] = v.w;
      }
    }
    for (int ii = 0; ii < 8; ii += 2) {
      int njj = jj, nii = ii + 2;
      if (nii >= 8) { njj++; nii = 0; }
      if (njj < 2) stage(buf^1, njj*128 + ig0 + nii);

      #pragma unroll
      for (int sc = 0; sc < 2; ++sc) {
        const __hip_bfloat16* bb = &blds[buf][sc*4096];
        bf16x8 bv[4];
        #pragma unroll
        for (int nf = 0; nf < 4; ++nf)
          bv[nf] = *(const bf16x8*)(bb + (ng*4 + nf)*512 + g*128 + lr*8);
        APack a[2];
        #pragma unroll
        for (int mf = 0; mf < 2; ++mf) {
          float xv = xlds[(mg*32 + mf*16 + lr)*8 + ii + sc];
          #pragma unroll
          for (int e = 0; e < 4; ++e)
            a[mf].d[e] = cvtpk_bf16(xv*yreg[mf][2*e], xv*yreg[mf][2*e+1]);
        }
        #pragma unroll
        for (int mf = 0; mf < 2; ++mf)
          #pragma unroll
          for (int nf = 0; nf < 4; ++nf)
            acc[mf][nf] = mfma16(a[mf].v, bv[nf], acc[mf][nf]);
      }
      __syncthreads();
      buf ^= 1;
    }
  }

  float* wp = wsW + ((size_t)s*2048 + b0)*128;
  #pragma unroll
  for (int mf = 0; mf < 2; ++mf) {
    #pragma unroll
    for (int nf = 0; nf < 4; ++nf) {
      int rb  = mg*32 + mf*16 + g*4;
      int col = ng*64 + nf*16 + lr;
      f32x4 v = acc[mf][nf];
      #pragma unroll
      for (int e = 0; e < 4; ++e) wp[(size_t)(rb+e)*128 + col] = v[e];
    }
  }
}

// ---------------------------------------------------------------------------
// Epilogue: sum partials + bias + relu -> expert rows.
// ---------------------------------------------------------------------------
__global__ __launch_bounds__(256) void epilogue_kernel(
    const float* __restrict__ wsX, const float* __restrict__ wsW,
    const float* __restrict__ b256, const float* __restrict__ b128,
    float* __restrict__ out)
{
  int idx = blockIdx.x*256 + threadIdx.x;
  if (idx >= BB*384) return;
  int b = idx / 384, c = idx - b*384;
  if (c < 256) {
    float acc = b256[c];
    #pragma unroll
    for (int k = 0; k < 16; ++k) acc += wsX[((size_t)k*BB + b)*256 + c];
    out[(size_t)b*EXPERT_W + X_OFF + c] = acc > 0.f ? acc : 0.f;
  } else {
    int cc = c - 256;
    float acc = b128[cc];
    #pragma unroll
    for (int k = 0; k < 16; ++k) acc += wsW[((size_t)k*BB + b)*128 + cc];
    out[(size_t)b*EXPERT_W + W_OFF + cc] = acc > 0.f ? acc : 0.f;
  }
}

// ---------------------------------------------------------------------------
// Fallback VALU kernels (round-2, verified-passing) used if ws too small.
// ---------------------------------------------------------------------------
static constexpr int NPAIR_X = 300 * 150;
static constexpr int CHX     = 128;

__global__ __launch_bounds__(256) void xuser_kernel(
    const int* __restrict__ inputs,
    const float* __restrict__ Wuf, const float* __restrict__ Wua,
    const float* __restrict__ Wfu, const float* __restrict__ Wau,
    const float* __restrict__ W256, const float* __restrict__ b256,
    float* __restrict__ out)
{
    __shared__ float xs[16][308];
    __shared__ float ys[16][308];
    __shared__ float xy[CHX][16];
    const int half = blockIdx.x & 1;
    const int bg   = blockIdx.x >> 1;
    const int b0   = bg * 16;
    const int t    = threadIdx.x;
    const int bl   = t & 15;
    const int kg   = t >> 4;
    const int kbase = half * 128 + kg * 8;
    for (int idx = t; idx < 16 * DD; idx += 256) {
        int bb = idx / DD;
        int c  = idx - bb * DD;
        int u = inputs[(b0+bb)*3 + 0];
        int f = inputs[(b0+bb)*3 + 1];
        int a = inputs[(b0+bb)*3 + 2];
        xs[bb][c]       = Wuf[u*DD + c];
        xs[bb][150 + c] = Wua[u*DD + c];
        ys[bb][c]       = Wfu[f*DD + c];
        ys[bb][150 + c] = Wau[a*DD + c];
    }
    float acc[8] = {0,0,0,0,0,0,0,0};
    for (int base = 0; base < NPAIR_X; base += CHX) {
        __syncthreads();
        #pragma unroll
        for (int r = 0; r < (CHX*16)/256; ++r) {
            int idx = t + r * 256;
            int pl  = idx >> 4;
            int bb  = idx & 15;
            int p   = base + pl;
            if (p < NPAIR_X) {
                int i = p / 150;
                int j = p - i * 150;
                xy[pl][bb] = xs[bb][i] * ys[bb][(i >= 150 ? 150 : 0) + j];
            }
        }
        __syncthreads();
        const int lim = min(CHX, NPAIR_X - base);
        const float* wp = W256 + base * 256 + kbase;
        for (int pl = 0; pl < lim; ++pl) {
            float sv = xy[pl][bl];
            const float4* w4 = (const float4*)(wp + pl * 256);
            float4 w0 = w4[0], w1 = w4[1];
            acc[0] = fmaf(sv, w0.x, acc[0]); acc[1] = fmaf(sv, w0.y, acc[1]);
            acc[2] = fmaf(sv, w0.z, acc[2]); acc[3] = fmaf(sv, w0.w, acc[3]);
            acc[4] = fmaf(sv, w1.x, acc[4]); acc[5] = fmaf(sv, w1.y, acc[5]);
            acc[6] = fmaf(sv, w1.z, acc[6]); acc[7] = fmaf(sv, w1.w, acc[7]);
        }
    }
    const int rowbase = (b0 + bl) * EXPERT_W + X_OFF;
    #pragma unroll
    for (int m = 0; m < 8; ++m) {
        float v = acc[m] + b256[kbase + m];
        out[rowbase + kbase + m] = (v > 0.f ? v : 0.f);
    }
}

static constexpr int NPAIR_W = 128 * 64;
static constexpr int CHW     = 256;

__global__ __launch_bounds__(256) void wuser_kernel(
    const int* __restrict__ inputs,
    const float* __restrict__ Wufd, const float* __restrict__ Wuad,
    const float* __restrict__ Wfud, const float* __restrict__ Waud,
    const float* __restrict__ W128, const float* __restrict__ b128,
    float* __restrict__ out)
{
    __shared__ float xs[8][132];
    __shared__ float ys[8][132];
    __shared__ float xy[CHW][8];
    const int bg = blockIdx.x;
    const int b0 = bg * 8;
    const int t  = threadIdx.x;
    const int bl = t & 7;
    const int kg = t >> 3;
    const int kbase = kg * 4;
    for (int idx = t; idx < 8 * DKK; idx += 256) {
        int bb = idx >> 6;
        int c  = idx & 63;
        int u = inputs[(b0+bb)*3 + 0];
        int f = inputs[(b0+bb)*3 + 1];
        int a = inputs[(b0+bb)*3 + 2];
        xs[bb][c]      = Wufd[u*DKK + c];
        xs[bb][64 + c] = Wuad[u*DKK + c];
        ys[bb][c]      = Wfud[f*DKK + c];
        ys[bb][64 + c] = Waud[a*DKK + c];
    }
    float acc[4] = {0,0,0,0};
    for (int base = 0; base < NPAIR_W; base += CHW) {
        __syncthreads();
        #pragma unroll
        for (int r = 0; r < (CHW*8)/256; ++r) {
            int idx = t + r * 256;
            int pl  = idx >> 3;
            int bb  = idx & 7;
            int p   = base + pl;
            int i = p >> 6;
            int j = p & 63;
            xy[pl][bb] = xs[bb][i] * ys[bb][(i >= 64 ? 64 : 0) + j];
        }
        __syncthreads();
        const float* wp = W128 + base * 128 + kbase;
        for (int pl = 0; pl < CHW; ++pl) {
            float sv = xy[pl][bl];
            float4 wv = *(const float4*)(wp + pl * 128);
            acc[0] = fmaf(sv, wv.x, acc[0]); acc[1] = fmaf(sv, wv.y, acc[1]);
            acc[2] = fmaf(sv, wv.z, acc[2]); acc[3] = fmaf(sv, wv.w, acc[3]);
        }
    }
    const int rowbase = (b0 + bl) * EXPERT_W + W_OFF;
    #pragma unroll
    for (int m = 0; m < 4; ++m) {
        float v = acc[m] + b128[kbase + m];
        out[rowbase + kbase + m] = (v > 0.f ? v : 0.f);
    }
}

// ---------------------------------------------------------------------------
extern "C" void kernel_launch(void* const* d_in, const int* in_sizes, int n_in,
                              void* d_out, int out_size, void* d_ws, size_t ws_size,
                              hipStream_t stream)
{
    const int*   inputs = (const int*)  d_in[0];
    const int*   shifts = (const int*)  d_in[1];
    const float* Wuf    = (const float*)d_in[2];
    const float* Wfu    = (const float*)d_in[3];
    const float* Wua    = (const float*)d_in[4];
    const float* Wau    = (const float*)d_in[5];
    const float* Wfe    = (const float*)d_in[6];
    const float* Wut    = (const float*)d_in[7];
    const float* Wuk1   = (const float*)d_in[8];
    const float* Wuk2   = (const float*)d_in[9];
    const float* Wft    = (const float*)d_in[10];
    const float* Wfk1   = (const float*)d_in[11];
    const float* Wfk2   = (const float*)d_in[12];
    const float* Wufd   = (const float*)d_in[13];
    const float* Wfud   = (const float*)d_in[14];
    const float* Wuad   = (const float*)d_in[15];
    const float* Waud   = (const float*)d_in[16];
    const float* W256   = (const float*)d_in[17];
    const float* b256   = (const float*)d_in[18];
    const float* W128   = (const float*)d_in[19];
    const float* b128   = (const float*)d_in[20];

    float* out = (float*)d_out;

    gather_kernel<<<BB, 256, 0, stream>>>(inputs, shifts,
        Wuf, Wfu, Wua, Wau, Wfe, Wut, Wuk1, Wuk2, Wft, Wfk1, Wfk2,
        Wufd, Wfud, Wuad, Waud, out);

    if (ws_size >= WS_NEED) {
        char* ws = (char*)d_ws;
        __hip_bfloat16* WtX = (__hip_bfloat16*)(ws + WTX_OFF);
        __hip_bfloat16* WtW = (__hip_bfloat16*)(ws + WTW_OFF);
        float* wsX = (float*)(ws + WSX_OFF);
        float* wsW = (float*)(ws + WSW_OFF);

        tile_pack_x<<<1500, 256, 0, stream>>>(W256, WtX);
        tile_pack_w<<<256, 128, 0, stream>>>(W128, WtW);

        xuser_mfma<<<512, 512, 0, stream>>>(inputs, Wuf, Wua, Wfu, Wau, WtX, wsX);
        wuser_mfma<<<256, 512, 0, stream>>>(inputs, Wufd, Wuad, Wfud, Waud, WtW, wsW);

        epilogue_kernel<<<(BB*384 + 255)/256, 256, 0, stream>>>(wsX, wsW, b256, b128, out);
    } else {
        xuser_kernel<<<256, 256, 0, stream>>>(inputs, Wuf, Wua, Wfu, Wau, W256, b256, out);
        wuser_kernel<<<256, 256, 0, stream>>>(inputs, Wufd, Wuad, Wfud, Waud, W128, b128, out);
    }
}

// Round 7
// 105.743 us; speedup vs baseline: 29.6046x; 1.0002x over previous
//
#include <hip/hip_runtime.h>
#include <hip/hip_bf16.h>
#include <stdint.h>

#define BB   2048
#define DD   150
#define DKK  64

static constexpr int EXPERT_W  = 1774;        // 5*150 + 10*64 + 256 + 128
static constexpr int X_OFF     = 1390;
static constexpr int W_OFF     = 1646;
static constexpr int EXPERT_SZ = BB * EXPERT_W;
static constexpr int OH_BASE   = EXPERT_SZ;
static constexpr int FM_BASE   = OH_BASE + BB * 3;

// ---- workspace layout (bytes) ----
// WtX: 1500 tiles (T = jj*300 + i) of 16384 B.
//      tile = [blk 0..15][ksub 0..3][nloc 0..15][e 0..7] bf16
//      value = W256[(i*150 + jj*32 + ksub*8 + e)][blk*16+nloc], 0 if j>=150
// WtW: 256 tiles (T = jj*128 + i) of 8192 B, same internal layout (blk 0..7).
static constexpr size_t WTX_OFF = 0;               // 24,576,000 B
static constexpr size_t WTW_OFF = 24576000;        //  2,097,152 B
static constexpr size_t WSX_OFF = 26673152;        // f32 [16][2048][256]
static constexpr size_t WSW_OFF = 60227584;        // f32 [16][2048][128]
static constexpr size_t WS_NEED = 77004800;

typedef __attribute__((ext_vector_type(8))) short bf16x8;
typedef __attribute__((ext_vector_type(4))) float f32x4;

union APack { int d[4]; bf16x8 v; };

__device__ __forceinline__ int cvtpk_bf16(float a, float b) {
  int r; asm("v_cvt_pk_bf16_f32 %0, %1, %2" : "=v"(r) : "v"(a), "v"(b)); return r;
}
__device__ __forceinline__ f32x4 mfma16(bf16x8 a, bf16x8 b, f32x4 c) {
  return __builtin_amdgcn_mfma_f32_16x16x32_bf16(a, b, c, 0, 0, 0);
}
// async global->LDS, 16B/lane; LDS dest must be wave-uniform base (lane adds lane*16)
__device__ __forceinline__ void gload16(const void* g, void* l) {
  __builtin_amdgcn_global_load_lds(
      (__attribute__((address_space(1))) void*)(g),
      (__attribute__((address_space(3))) void*)(l), 16, 0, 0);
}

// ---------------------------------------------------------------------------
// Kernel 1: gathers -> expert row segments, one_hot, fm copies (f32 out).
// ---------------------------------------------------------------------------
__global__ __launch_bounds__(256) void gather_kernel(
    const int* __restrict__ inputs, const int* __restrict__ shifts,
    const float* __restrict__ Wuf, const float* __restrict__ Wfu,
    const float* __restrict__ Wua, const float* __restrict__ Wau,
    const float* __restrict__ Wfe,
    const float* __restrict__ Wut, const float* __restrict__ Wuk1, const float* __restrict__ Wuk2,
    const float* __restrict__ Wft, const float* __restrict__ Wfk1, const float* __restrict__ Wfk2,
    const float* __restrict__ Wufd, const float* __restrict__ Wfud,
    const float* __restrict__ Wuad, const float* __restrict__ Waud,
    float* __restrict__ out)
{
    const int b = blockIdx.x;
    const int u = inputs[b*3 + 0];
    const int f = inputs[b*3 + 1];
    const int a = inputs[b*3 + 2];
    float* row = out + b * EXPERT_W;
    float* fm  = out + FM_BASE;
    const int t = threadIdx.x;

    for (int c = t; c < DD; c += 256) {
        float ufe = Wuf[u*DD + c];
        float uae = Wua[u*DD + c];
        float fue = Wfu[f*DD + c];
        float fee = Wfe[f*DD + c];
        float aue = Wau[a*DD + c];
        row[0    + c] = ufe;
        row[150  + c] = uae;
        row[620  + c] = fue;
        row[898  + c] = fee;
        row[1176 + c] = aue;
        fm[0*BB*DD + b*DD + c] = ufe;
        fm[1*BB*DD + b*DD + c] = uae;
        fm[2*BB*DD + b*DD + c] = fue;
        fm[3*BB*DD + b*DD + c] = aue;
    }
    for (int c = t; c < DKK; c += 256) {
        row[300  + c] = Wut [u*DKK + c];
        row[364  + c] = Wuk1[u*DKK + c];
        row[428  + c] = Wuk2[u*DKK + c];
        row[492  + c] = Wufd[u*DKK + c];
        row[556  + c] = Wuad[u*DKK + c];
        row[770  + c] = Wft [f*DKK + c];
        row[834  + c] = Wfk1[f*DKK + c];
        row[1048 + c] = Wfk2[f*DKK + c];
        row[1112 + c] = Wfud[f*DKK + c];
        row[1326 + c] = Waud[a*DKK + c];
    }
    if (t < 3) {
        out[OH_BASE + b*3 + t] = (float)(inputs[b*3 + t] + shifts[t]);
    }
}

// ---------------------------------------------------------------------------
// Tile-pack W256 -> WtX: one block per tile T = jj*300 + i. 256 thr (t = n).
// ---------------------------------------------------------------------------
__global__ __launch_bounds__(256) void tile_pack_x(
    const float* __restrict__ W, __hip_bfloat16* __restrict__ Wt)
{
  const int T  = blockIdx.x;
  const int jj = T / 300;
  const int i  = T - jj*300;
  const int t  = threadIdx.x;           // n = blk*16 + nloc
  float v[32];
  const float* src = W + ((size_t)i*150 + jj*32)*256 + t;
  #pragma unroll
  for (int jl = 0; jl < 32; ++jl) {
    int j = jj*32 + jl;
    v[jl] = (j < 150) ? src[(size_t)jl*256] : 0.f;
  }
  const int blk = t >> 4, nloc = t & 15;
  char* dst = (char*)Wt + (size_t)T*16384 + (size_t)(blk*512 + nloc*8)*2;
  #pragma unroll
  for (int ksub = 0; ksub < 4; ++ksub) {
    int pk0 = cvtpk_bf16(v[ksub*8+0], v[ksub*8+1]);
    int pk1 = cvtpk_bf16(v[ksub*8+2], v[ksub*8+3]);
    int pk2 = cvtpk_bf16(v[ksub*8+4], v[ksub*8+5]);
    int pk3 = cvtpk_bf16(v[ksub*8+6], v[ksub*8+7]);
    *(int4*)(dst + (size_t)ksub*256) = make_int4(pk0, pk1, pk2, pk3);
  }
}

// ---------------------------------------------------------------------------
// Tile-pack W128 -> WtW: one block per tile T = jj*128 + i. 128 thr (t = n).
// ---------------------------------------------------------------------------
__global__ __launch_bounds__(128) void tile_pack_w(
    const float* __restrict__ W, __hip_bfloat16* __restrict__ Wt)
{
  const int T  = blockIdx.x;
  const int jj = T >> 7;
  const int i  = T & 127;
  const int t  = threadIdx.x;
  float v[32];
  const float* src = W + ((size_t)i*64 + jj*32)*128 + t;
  #pragma unroll
  for (int jl = 0; jl < 32; ++jl) v[jl] = src[(size_t)jl*128];
  const int blk = t >> 4, nloc = t & 15;
  char* dst = (char*)Wt + (size_t)T*8192 + (size_t)(blk*512 + nloc*8)*2;
  #pragma unroll
  for (int ksub = 0; ksub < 4; ++ksub) {
    int pk0 = cvtpk_bf16(v[ksub*8+0], v[ksub*8+1]);
    int pk1 = cvtpk_bf16(v[ksub*8+2], v[ksub*8+3]);
    int pk2 = cvtpk_bf16(v[ksub*8+4], v[ksub*8+5]);
    int pk3 = cvtpk_bf16(v[ksub*8+6], v[ksub*8+7]);
    *(int4*)(dst + (size_t)ksub*256) = make_int4(pk0, pk1, pk2, pk3);
  }
}

// ---------------------------------------------------------------------------
// xuser MFMA v6: counted-vmcnt pipeline (T3/T4). grid 512 = 16 mb x 16 s x 2 h.
// 512 thr = 8 waves (4 mg x 2 ng); wave = 2 mf x 4 nf. Pair = two 8KB
// half-tiles per barrier, double-buffered; stage pair p+2 while p+1 in flight;
// s_waitcnt vmcnt(2) (never 0 except last) before each barrier.
// ---------------------------------------------------------------------------
__global__ __launch_bounds__(512, 4) void xuser_mfma(
    const int* __restrict__ inputs,
    const float* __restrict__ Wuf, const float* __restrict__ Wua,
    const float* __restrict__ Wfu, const float* __restrict__ Wau,
    const __hip_bfloat16* __restrict__ WtXt, float* __restrict__ wsX)
{
  __shared__ float xlds[128*20];                          // 10 KB
  __shared__ __align__(16) __hip_bfloat16 blds[2][8192];  // 2 x 16 KB

  const int bid = blockIdx.x;
  const int h  = bid & 1;
  const int s  = (bid >> 1) & 15;
  const int mb = bid >> 5;
  const int b0 = mb * 128;
  const bool upper = s >= 8;
  const int sl  = upper ? s - 8 : s;
  const int i0l = sl * 19;
  const int cnt = (150 - i0l) < 19 ? (150 - i0l) : 19;   // 19 or 17
  const int ig0 = i0l + (upper ? 150 : 0);               // global i of chunk 0
  const int tid = threadIdx.x;

  const float* X = upper ? Wua : Wuf;
  const float* Y = upper ? Wau : Wfu;
  const int yoff = upper ? 2 : 1;

  // stage x [128 rows][20 ii]
  for (int k = tid; k < 128*20; k += 512) {
    int r = k / 20, ii = k - r*20;
    float v = 0.f;
    if (ii < cnt) v = X[(size_t)inputs[(b0+r)*3]*150 + i0l + ii];
    xlds[k] = v;
  }

  const int lane = tid & 63;
  const int w  = tid >> 6;
  const int mg = w >> 1;        // 0..3 (32 rows each)
  const int ng = w & 1;         // 0..1 (64 cols each)
  const int lr = lane & 15;
  const int g  = lane >> 4;

  int yid[2];
  #pragma unroll
  for (int mf = 0; mf < 2; ++mf)
    yid[mf] = inputs[(size_t)(b0 + mg*32 + mf*16 + lr)*3 + yoff];

  const char* wtb = (const char*)WtXt + (size_t)h*8192;
  const unsigned wdst = (unsigned)(tid & ~63) * 16;   // wave-uniform LDS byte base

  // stage pair (tiles T, T+1) into buffer: exactly 2 gloads, always
  // (second half-tile may be out of this slice's range; never consumed then,
  //  and the address stays inside the workspace)
  auto stageT = [&](int bufi, int T) {
    const char* sp = wtb + (size_t)T*16384 + (size_t)tid*16;
    char* dp = (char*)&blds[bufi][0] + wdst;
    gload16(sp,         dp);
    gload16(sp + 16384, dp + 8192);
  };

  f32x4 acc[2][4];
  #pragma unroll
  for (int i = 0; i < 2; ++i)
    #pragma unroll
    for (int j = 0; j < 4; ++j) acc[i][j] = (f32x4){0.f,0.f,0.f,0.f};

  const int PJ = (cnt + 1) >> 1;     // pairs per jj (10 or 9)
  const int P  = 5 * PJ;

  // prologue: pairs 0 and 1 (jj=0, ii=0 and ii=2; cnt >= 17 so both valid)
  stageT(0, ig0);
  stageT(1, ig0 + 2);

  int jjc = 0, iic = 0;   // coords of pair p
  int jjs = 0, iis = 4;   // coords of pair p+2
  int yjj = -1;
  float yreg[2][8];

  for (int p = 0; p < P; ++p) {
    if (jjc != yjj) {
      yjj = jjc;
      const int jb = jjc*32 + g*8;
      #pragma unroll
      for (int mf = 0; mf < 2; ++mf) {
        const float* yp = Y + (size_t)yid[mf]*150;
        if (jb + 8 <= 150) {
          #pragma unroll
          for (int hh = 0; hh < 4; ++hh) {
            float2 vv = *(const float2*)(yp + jb + 2*hh);
            yreg[mf][2*hh]   = vv.x;
            yreg[mf][2*hh+1] = vv.y;
          }
        } else {
          #pragma unroll
          for (int e = 0; e < 8; ++e)
            yreg[mf][e] = (jb + e < 150) ? yp[jb + e] : 0.f;
        }
      }
    }
    // pair p's 2 loads are the oldest outstanding; pair p+1's 2 are the newest
    if (p + 1 < P) asm volatile("s_waitcnt vmcnt(2)" ::: "memory");
    else           asm volatile("s_waitcnt vmcnt(0)" ::: "memory");
    __builtin_amdgcn_s_barrier();          // all waves' stages for pair p done
    __builtin_amdgcn_sched_barrier(0);

    const int buf = p & 1;
    const int rem = cnt - iic;
    #pragma unroll
    for (int sc = 0; sc < 2; ++sc) {
      if (sc == 1 && rem < 2) break;
      const __hip_bfloat16* bb = &blds[buf][sc*4096];
      bf16x8 bv[4];
      #pragma unroll
      for (int nf = 0; nf < 4; ++nf)
        bv[nf] = *(const bf16x8*)(bb + (ng*4 + nf)*512 + g*128 + lr*8);
      APack a[2];
      #pragma unroll
      for (int mf = 0; mf < 2; ++mf) {
        float xv = xlds[(mg*32 + mf*16 + lr)*20 + iic + sc];
        #pragma unroll
        for (int e = 0; e < 4; ++e)
          a[mf].d[e] = cvtpk_bf16(xv*yreg[mf][2*e], xv*yreg[mf][2*e+1]);
      }
      #pragma unroll
      for (int mf = 0; mf < 2; ++mf)
        #pragma unroll
        for (int nf = 0; nf < 4; ++nf)
          acc[mf][nf] = mfma16(a[mf].v, bv[nf], acc[mf][nf]);
    }

    __builtin_amdgcn_s_barrier();          // all waves done reading buf
    if (p + 2 < P) stageT(buf, jjs*300 + ig0 + iis);

    iic += 2; if (iic >= cnt) { iic = 0; ++jjc; }
    iis += 2; if (iis >= cnt) { iis = 0; ++jjs; }
  }

  // store partials: C/D layout: col = lane&15, row = 4*(lane>>4)+e
  float* wp = wsX + ((size_t)s*2048 + b0)*256;
  #pragma unroll
  for (int mf = 0; mf < 2; ++mf) {
    #pragma unroll
    for (int nf = 0; nf < 4; ++nf) {
      int rb  = mg*32 + mf*16 + g*4;
      int col = h*128 + ng*64 + nf*16 + lr;
      f32x4 v = acc[mf][nf];
      #pragma unroll
      for (int e = 0; e < 4; ++e) wp[(size_t)(rb+e)*256 + col] = v[e];
    }
  }
}

// ---------------------------------------------------------------------------
// wuser MFMA v6: counted-vmcnt pipeline. grid 256 = 16 mb x 16 s.
// 8 waves (4 mg x 2 ng); wave = 2 mf x 4 nf. Pair = two 8KB tiles/barrier.
// ---------------------------------------------------------------------------
__global__ __launch_bounds__(512, 4) void wuser_mfma(
    const int* __restrict__ inputs,
    const float* __restrict__ Wufd, const float* __restrict__ Wuad,
    const float* __restrict__ Wfud, const float* __restrict__ Waud,
    const __hip_bfloat16* __restrict__ WtWt, float* __restrict__ wsW)
{
  __shared__ float xlds[128*8];                           // 4 KB
  __shared__ __align__(16) __hip_bfloat16 blds[2][8192];  // 2 x 16 KB

  const int mb = blockIdx.x >> 4;
  const int s  = blockIdx.x & 15;
  const int b0 = mb * 128;
  const bool upper = s >= 8;
  const int i0l = (s & 7) * 8;
  const int ig0 = i0l + (upper ? 64 : 0);
  const int tid = threadIdx.x;

  const float* X = upper ? Wuad : Wufd;
  const float* Y = upper ? Waud : Wfud;
  const int yoff = upper ? 2 : 1;

  for (int k = tid; k < 128*8; k += 512) {
    int r = k >> 3, ii = k & 7;
    xlds[k] = X[(size_t)inputs[(size_t)(b0+r)*3]*64 + i0l + ii];
  }

  const int lane = tid & 63;
  const int w  = tid >> 6;
  const int mg = w >> 1;        // 0..3
  const int ng = w & 1;         // 0..1 (64 cols each)
  const int lr = lane & 15;
  const int g  = lane >> 4;

  int yid[2];
  #pragma unroll
  for (int mf = 0; mf < 2; ++mf)
    yid[mf] = inputs[(size_t)(b0 + mg*32 + mf*16 + lr)*3 + yoff];

  const char* wtb = (const char*)WtWt;
  const unsigned wdst = (unsigned)(tid & ~63) * 16;

  auto stageT = [&](int bufi, int T) {   // tiles T, T+1 (always valid: ii+1 <= 7)
    const char* sp = wtb + (size_t)T*8192 + (size_t)tid*16;
    char* dp = (char*)&blds[bufi][0] + wdst;
    gload16(sp,        dp);
    gload16(sp + 8192, dp + 8192);
  };

  f32x4 acc[2][4];
  #pragma unroll
  for (int i = 0; i < 2; ++i)
    #pragma unroll
    for (int j = 0; j < 4; ++j) acc[i][j] = (f32x4){0.f,0.f,0.f,0.f};

  // pairs: P = 8 (jj in 0..1, ii = 0,2,4,6)
  stageT(0, ig0);
  stageT(1, ig0 + 2);

  int jjc = 0, iic = 0;
  int jjs = 0, iis = 4;
  int yjj = -1;
  float yreg[2][8];

  for (int p = 0; p < 8; ++p) {
    if (jjc != yjj) {
      yjj = jjc;
      const int jb = jjc*32 + g*8;       // <= 56; +8 = 64 = row length, safe
      #pragma unroll
      for (int mf = 0; mf < 2; ++mf) {
        const float* yp = Y + (size_t)yid[mf]*64 + jb;
        #pragma unroll
        for (int hh = 0; hh < 2; ++hh) {
          float4 v = *(const float4*)(yp + hh*4);
          yreg[mf][hh*4]   = v.x;
          yreg[mf][hh*4+1] = v.y;
          yreg[mf][hh*4+2] = v.z;
          yreg[mf][hh*4+3] = v.w;
        }
      }
    }
    if (p + 1 < 8) asm volatile("s_waitcnt vmcnt(2)" ::: "memory");
    else           asm volatile("s_waitcnt vmcnt(0)" ::: "memory");
    __builtin_amdgcn_s_barrier();
    __builtin_amdgcn_sched_barrier(0);

    const int buf = p & 1;
    #pragma unroll
    for (int sc = 0; sc < 2; ++sc) {
      const __hip_bfloat16* bb = &blds[buf][sc*4096];
      bf16x8 bv[4];
      #pragma unroll
      for (int nf = 0; nf < 4; ++nf)
        bv[nf] = *(const bf16x8*)(bb + (ng*4 + nf)*512 + g*128 + lr*8);
      APack a[2];
      #pragma unroll
      for (int mf = 0; mf < 2; ++mf) {
        float xv = xlds[(mg*32 + mf*16 + lr)*8 + iic + sc];
        #pragma unroll
        for (int e = 0; e < 4; ++e)
          a[mf].d[e] = cvtpk_bf16(xv*yreg[mf][2*e], xv*yreg[mf][2*e+1]);
      }
      #pragma unroll
      for (int mf = 0; mf < 2; ++mf)
        #pragma unroll
        for (int nf = 0; nf < 4; ++nf)
          acc[mf][nf] = mfma16(a[mf].v, bv[nf], acc[mf][nf]);
    }

    __builtin_amdgcn_s_barrier();
    if (p + 2 < 8) stageT(buf, jjs*128 + ig0 + iis);

    iic += 2; if (iic >= 8) { iic = 0; ++jjc; }
    iis += 2; if (iis >= 8) { iis = 0; ++jjs; }
  }

  float* wp = wsW + ((size_t)s*2048 + b0)*128;
  #pragma unroll
  for (int mf = 0; mf < 2; ++mf) {
    #pragma unroll
    for (int nf = 0; nf < 4; ++nf) {
      int rb  = mg*32 + mf*16 + g*4;
      int col = ng*64 + nf*16 + lr;
      f32x4 v = acc[mf][nf];
      #pragma unroll
      for (int e = 0; e < 4; ++e) wp[(size_t)(rb+e)*128 + col] = v[e];
    }
  }
}

// ---------------------------------------------------------------------------
// Epilogue: sum partials + bias + relu -> expert rows.
// ---------------------------------------------------------------------------
__global__ __launch_bounds__(256) void epilogue_kernel(
    const float* __restrict__ wsX, const float* __restrict__ wsW,
    const float* __restrict__ b256, const float* __restrict__ b128,
    float* __restrict__ out)
{
  int idx = blockIdx.x*256 + threadIdx.x;
  if (idx >= BB*384) return;
  int b = idx / 384, c = idx - b*384;
  if (c < 256) {
    float acc = b256[c];
    #pragma unroll
    for (int k = 0; k < 16; ++k) acc += wsX[((size_t)k*BB + b)*256 + c];
    out[(size_t)b*EXPERT_W + X_OFF + c] = acc > 0.f ? acc : 0.f;
  } else {
    int cc = c - 256;
    float acc = b128[cc];
    #pragma unroll
    for (int k = 0; k < 16; ++k) acc += wsW[((size_t)k*BB + b)*128 + cc];
    out[(size_t)b*EXPERT_W + W_OFF + cc] = acc > 0.f ? acc : 0.f;
  }
}

// ---------------------------------------------------------------------------
// Fallback VALU kernels (round-2, verified-passing) used if ws too small.
// ---------------------------------------------------------------------------
static constexpr int NPAIR_X = 300 * 150;
static constexpr int CHX     = 128;

__global__ __launch_bounds__(256) void xuser_kernel(
    const int* __restrict__ inputs,
    const float* __restrict__ Wuf, const float* __restrict__ Wua,
    const float* __restrict__ Wfu, const float* __restrict__ Wau,
    const float* __restrict__ W256, const float* __restrict__ b256,
    float* __restrict__ out)
{
    __shared__ float xs[16][308];
    __shared__ float ys[16][308];
    __shared__ float xy[CHX][16];
    const int half = blockIdx.x & 1;
    const int bg   = blockIdx.x >> 1;
    const int b0   = bg * 16;
    const int t    = threadIdx.x;
    const int bl   = t & 15;
    const int kg   = t >> 4;
    const int kbase = half * 128 + kg * 8;
    for (int idx = t; idx < 16 * DD; idx += 256) {
        int bb = idx / DD;
        int c  = idx - bb * DD;
        int u = inputs[(b0+bb)*3 + 0];
        int f = inputs[(b0+bb)*3 + 1];
        int a = inputs[(b0+bb)*3 + 2];
        xs[bb][c]       = Wuf[u*DD + c];
        xs[bb][150 + c] = Wua[u*DD + c];
        ys[bb][c]       = Wfu[f*DD + c];
        ys[bb][150 + c] = Wau[a*DD + c];
    }
    float acc[8] = {0,0,0,0,0,0,0,0};
    for (int base = 0; base < NPAIR_X; base += CHX) {
        __syncthreads();
        #pragma unroll
        for (int r = 0; r < (CHX*16)/256; ++r) {
            int idx = t + r * 256;
            int pl  = idx >> 4;
            int bb  = idx & 15;
            int p   = base + pl;
            if (p < NPAIR_X) {
                int i = p / 150;
                int j = p - i * 150;
                xy[pl][bb] = xs[bb][i] * ys[bb][(i >= 150 ? 150 : 0) + j];
            }
        }
        __syncthreads();
        const int lim = min(CHX, NPAIR_X - base);
        const float* wp = W256 + base * 256 + kbase;
        for (int pl = 0; pl < lim; ++pl) {
            float sv = xy[pl][bl];
            const float4* w4 = (const float4*)(wp + pl * 256);
            float4 w0 = w4[0], w1 = w4[1];
            acc[0] = fmaf(sv, w0.x, acc[0]); acc[1] = fmaf(sv, w0.y, acc[1]);
            acc[2] = fmaf(sv, w0.z, acc[2]); acc[3] = fmaf(sv, w0.w, acc[3]);
            acc[4] = fmaf(sv, w1.x, acc[4]); acc[5] = fmaf(sv, w1.y, acc[5]);
            acc[6] = fmaf(sv, w1.z, acc[6]); acc[7] = fmaf(sv, w1.w, acc[7]);
        }
    }
    const int rowbase = (b0 + bl) * EXPERT_W + X_OFF;
    #pragma unroll
    for (int m = 0; m < 8; ++m) {
        float v = acc[m] + b256[kbase + m];
        out[rowbase + kbase + m] = (v > 0.f ? v : 0.f);
    }
}

static constexpr int NPAIR_W = 128 * 64;
static constexpr int CHW     = 256;

__global__ __launch_bounds__(256) void wuser_kernel(
    const int* __restrict__ inputs,
    const float* __restrict__ Wufd, const float* __restrict__ Wuad,
    const float* __restrict__ Wfud, const float* __restrict__ Waud,
    const float* __restrict__ W128, const float* __restrict__ b128,
    float* __restrict__ out)
{
    __shared__ float xs[8][132];
    __shared__ float ys[8][132];
    __shared__ float xy[CHW][8];
    const int bg = blockIdx.x;
    const int b0 = bg * 8;
    const int t  = threadIdx.x;
    const int bl = t & 7;
    const int kg = t >> 3;
    const int kbase = kg * 4;
    for (int idx = t; idx < 8 * DKK; idx += 256) {
        int bb = idx >> 6;
        int c  = idx & 63;
        int u = inputs[(b0+bb)*3 + 0];
        int f = inputs[(b0+bb)*3 + 1];
        int a = inputs[(b0+bb)*3 + 2];
        xs[bb][c]      = Wufd[u*DKK + c];
        xs[bb][64 + c] = Wuad[u*DKK + c];
        ys[bb][c]      = Wfud[f*DKK + c];
        ys[bb][64 + c] = Waud[a*DKK + c];
    }
    float acc[4] = {0,0,0,0};
    for (int base = 0; base < NPAIR_W; base += CHW) {
        __syncthreads();
        #pragma unroll
        for (int r = 0; r < (CHW*8)/256; ++r) {
            int idx = t + r * 256;
            int pl  = idx >> 3;
            int bb  = idx & 7;
            int p   = base + pl;
            int i = p >> 6;
            int j = p & 63;
            xy[pl][bb] = xs[bb][i] * ys[bb][(i >= 64 ? 64 : 0) + j];
        }
        __syncthreads();
        const float* wp = W128 + base * 128 + kbase;
        for (int pl = 0; pl < CHW; ++pl) {
            float sv = xy[pl][bl];
            float4 wv = *(const float4*)(wp + pl * 128);
            acc[0] = fmaf(sv, wv.x, acc[0]); acc[1] = fmaf(sv, wv.y, acc[1]);
            acc[2] = fmaf(sv, wv.z, acc[2]); acc[3] = fmaf(sv, wv.w, acc[3]);
        }
    }
    const int rowbase = (b0 + bl) * EXPERT_W + W_OFF;
    #pragma unroll
    for (int m = 0; m < 4; ++m) {
        float v = acc[m] + b128[kbase + m];
        out[rowbase + kbase + m] = (v > 0.f ? v : 0.f);
    }
}

// ---------------------------------------------------------------------------
extern "C" void kernel_launch(void* const* d_in, const int* in_sizes, int n_in,
                              void* d_out, int out_size, void* d_ws, size_t ws_size,
                              hipStream_t stream)
{
    const int*   inputs = (const int*)  d_in[0];
    const int*   shifts = (const int*)  d_in[1];
    const float* Wuf    = (const float*)d_in[2];
    const float* Wfu    = (const float*)d_in[3];
    const float* Wua    = (const float*)d_in[4];
    const float* Wau    = (const float*)d_in[5];
    const float* Wfe    = (const float*)d_in[6];
    const float* Wut    = (const float*)d_in[7];
    const float* Wuk1   = (const float*)d_in[8];
    const float* Wuk2   = (const float*)d_in[9];
    const float* Wft    = (const float*)d_in[10];
    const float* Wfk1   = (const float*)d_in[11];
    const float* Wfk2   = (const float*)d_in[12];
    const float* Wufd   = (const float*)d_in[13];
    const float* Wfud   = (const float*)d_in[14];
    const float* Wuad   = (const float*)d_in[15];
    const float* Waud   = (const float*)d_in[16];
    const float* W256   = (const float*)d_in[17];
    const float* b256   = (const float*)d_in[18];
    const float* W128   = (const float*)d_in[19];
    const float* b128   = (const float*)d_in[20];

    float* out = (float*)d_out;

    gather_kernel<<<BB, 256, 0, stream>>>(inputs, shifts,
        Wuf, Wfu, Wua, Wau, Wfe, Wut, Wuk1, Wuk2, Wft, Wfk1, Wfk2,
        Wufd, Wfud, Wuad, Waud, out);

    if (ws_size >= WS_NEED) {
        char* ws = (char*)d_ws;
        __hip_bfloat16* WtX = (__hip_bfloat16*)(ws + WTX_OFF);
        __hip_bfloat16* WtW = (__hip_bfloat16*)(ws + WTW_OFF);
        float* wsX = (float*)(ws + WSX_OFF);
        float* wsW = (float*)(ws + WSW_OFF);

        tile_pack_x<<<1500, 256, 0, stream>>>(W256, WtX);
        tile_pack_w<<<256, 128, 0, stream>>>(W128, WtW);

        xuser_mfma<<<512, 512, 0, stream>>>(inputs, Wuf, Wua, Wfu, Wau, WtX, wsX);
        wuser_mfma<<<256, 512, 0, stream>>>(inputs, Wufd, Wuad, Wfud, Waud, WtW, wsW);

        epilogue_kernel<<<(BB*384 + 255)/256, 256, 0, stream>>>(wsX, wsW, b256, b128, out);
    } else {
        xuser_kernel<<<256, 256, 0, stream>>>(inputs, Wuf, Wua, Wfu, Wau, W256, b256, out);
        wuser_kernel<<<256, 256, 0, stream>>>(inputs, Wufd, Wuad, Wfud, Waud, W128, b128, out);
    }
}